// Round 3
// baseline (869.076 us; speedup 1.0000x reference)
//
#include <hip/hip_runtime.h>
#include <hip/hip_bf16.h>
#include <stdint.h>

#define L_SEQ 4096
#define H_DIM 768
#define N_HEADS 12
#define D_HEAD 64
#define N_CHUNK 32
#define CHUNK 128
#define FF_DIM 3072
#define OUT_DIM 384
#define BATCH 2
#define EPS_LN 1e-5f
#define M_ROWS (BATCH * L_SEQ)   /* 8192 */
#define QKV_LD (3 * H_DIM)       /* 2304 */
#define NSEG 16                   /* global-row segments: 4096/256 */

typedef unsigned short u16;
typedef __bf16 bx8 __attribute__((ext_vector_type(8)));
typedef float fx4 __attribute__((ext_vector_type(4)));
typedef u16 ux8 __attribute__((ext_vector_type(8)));

__device__ __forceinline__ u16 f2bf(float f) {
  union { float f; unsigned u; } x; x.f = f;
  unsigned r = x.u + 0x7fffu + ((x.u >> 16) & 1u);
  return (u16)(r >> 16);
}
__device__ __forceinline__ float bf2f(u16 v) {
  union { unsigned u; float f; } x; x.u = ((unsigned)v) << 16;
  return x.f;
}

__device__ __forceinline__ void gload16(const void* g, void* l) {
  __builtin_amdgcn_global_load_lds((const __attribute__((address_space(1))) void*)g,
                                   (__attribute__((address_space(3))) void*)l, 16, 0, 0);
}

// =====================================================================
// 256x256 deep-pipelined GEMM (8 waves, BK=64, 2-deep LDS dbuf, 4 phases
// per K-tile, counted vmcnt, setprio around MFMA). C = A @ Bt^T + bias.
// LDS layout per buffer: A[ks][256][32], B[ks][256][32] bf16 (k-planed:
// conflict-free ds_read_b128 and contiguous 16KB k-half staging units).
// Stage schedule (tile t, buffers cur=t&1):
//   ph0: stage (t+1,k1,A)->nxt   reads ks0 A(m0-3)+B      mfma m0-3
//   ph1: stage (t+1,k1,B)->nxt   reads ks0 A(m4-7)        mfma m4-7   vmcnt(8)
//   ph2: stage (t+2,k0,A)->cur   reads ks1 A(m0-3)+B      mfma m0-3
//   ph3: stage (t+2,k0,B)->cur   reads ks1 A(m4-7)        mfma m4-7   vmcnt(8)
// k-half of cur overwritten in ph2/3 is only read in ph0/1 (barrier-ordered).
// =====================================================================
template<int OUT_BF16, int DO_GELU>
__global__ __launch_bounds__(512, 2)
void gemm256_kernel(const u16* __restrict__ A, const u16* __restrict__ Bt,
                    const float* __restrict__ bias,
                    float* __restrict__ Cf, u16* __restrict__ Cb,
                    int N, int K)
{
  __shared__ __align__(16) u16 lds[65536];   // 128 KiB: 2 buf x (A 32K + B 32K)
  const int tid = threadIdx.x;
  const int lane = tid & 63, w = tid >> 6;
  const int c16 = lane & 15, g = lane >> 4;
  const int wm = w >> 2, wn = w & 3;         // 2 x 4 wave grid, per-wave 128x64

  const int nbn = N >> 8;
  int id = blockIdx.x;
  id = (id & 7) * (gridDim.x >> 3) + (id >> 3);   // XCD swizzle (grids %8==0)
  const int bm = id / nbn, bn = id % nbn;
  const int NT = K >> 6;                     // K-tiles of 64 (NT >= 2)

  // staging source: lane covers row (w*32 + j*16 + l/4), 16B chunk (l&3)
  const int srow = w * 32 + (lane >> 2);
  const int scol = (lane & 3) * 8;
  const u16* sA0 = A  + (size_t)(bm * 256 + srow) * K + scol;
  const u16* sA1 = sA0 + (size_t)16 * K;
  const u16* sB0 = Bt + (size_t)(bn * 256 + srow) * K + scol;
  const u16* sB1 = sB0 + (size_t)16 * K;
  const int dst0 = w * 1024, dst1 = dst0 + 512;   // u16 offsets (wave-uniform)

#define SGA(buf, ks, t) do { const int _o = (buf)*32768 + (ks)*8192; \
    gload16(sA0 + (size_t)(t)*64 + (ks)*32, &lds[_o + dst0]); \
    gload16(sA1 + (size_t)(t)*64 + (ks)*32, &lds[_o + dst1]); } while(0)
#define SGB(buf, ks, t) do { const int _o = (buf)*32768 + (ks)*8192 + 16384; \
    gload16(sB0 + (size_t)(t)*64 + (ks)*32, &lds[_o + dst0]); \
    gload16(sB1 + (size_t)(t)*64 + (ks)*32, &lds[_o + dst1]); } while(0)
#define BARRIER() asm volatile("s_barrier" ::: "memory")

  fx4 acc[8][4] = {};
  const int aoff = (wm * 128 + c16) * 32 + g * 8;           // + m*512, +ks*8192
  const int boff = 16384 + (wn * 64 + c16) * 32 + g * 8;    // + n*512, +ks*8192

  // prologue: t0{k0,k1} + t1{k0}; wait only for t0k0 (8 newer stay in flight)
  SGA(0, 0, 0); SGB(0, 0, 0); SGA(0, 1, 0); SGB(0, 1, 0);
  SGA(1, 0, 1); SGB(1, 0, 1);
  asm volatile("s_waitcnt vmcnt(8)" ::: "memory");
  BARRIER();

  for (int t = 0; t < NT; ++t) {
    const int cur = t & 1, nxt = cur ^ 1;
    const int cb = cur * 32768;
    bx8 afr[4], bfr[4];

    // ---------------- phase 0: ks=0, m0-3 ----------------
    if (t + 1 < NT) SGA(nxt, 1, t + 1);
    #pragma unroll
    for (int n = 0; n < 4; n++) bfr[n] = *(const bx8*)&lds[cb + boff + n * 512];
    #pragma unroll
    for (int m = 0; m < 4; m++) afr[m] = *(const bx8*)&lds[cb + aoff + m * 512];
    BARRIER();
    __builtin_amdgcn_s_setprio(1);
    #pragma unroll
    for (int m = 0; m < 4; m++)
      #pragma unroll
      for (int n = 0; n < 4; n++)
        acc[m][n] = __builtin_amdgcn_mfma_f32_16x16x32_bf16(afr[m], bfr[n], acc[m][n], 0, 0, 0);
    __builtin_amdgcn_s_setprio(0);
    BARRIER();

    // ---------------- phase 1: ks=0, m4-7 ----------------
    if (t + 1 < NT) SGB(nxt, 1, t + 1);
    #pragma unroll
    for (int m = 0; m < 4; m++) afr[m] = *(const bx8*)&lds[cb + aoff + (4 + m) * 512];
    BARRIER();
    __builtin_amdgcn_s_setprio(1);
    #pragma unroll
    for (int m = 0; m < 4; m++)
      #pragma unroll
      for (int n = 0; n < 4; n++)
        acc[4 + m][n] = __builtin_amdgcn_mfma_f32_16x16x32_bf16(afr[m], bfr[n], acc[4 + m][n], 0, 0, 0);
    __builtin_amdgcn_s_setprio(0);
    if (t + 1 < NT) asm volatile("s_waitcnt vmcnt(8)" ::: "memory");
    else            asm volatile("s_waitcnt vmcnt(0)" ::: "memory");
    BARRIER();   // k1 of cur now ready for all waves

    // ---------------- phase 2: ks=1, m0-3 ----------------
    if (t + 2 < NT) SGA(cur, 0, t + 2);
    #pragma unroll
    for (int n = 0; n < 4; n++) bfr[n] = *(const bx8*)&lds[cb + 8192 + boff + n * 512];
    #pragma unroll
    for (int m = 0; m < 4; m++) afr[m] = *(const bx8*)&lds[cb + 8192 + aoff + m * 512];
    BARRIER();
    __builtin_amdgcn_s_setprio(1);
    #pragma unroll
    for (int m = 0; m < 4; m++)
      #pragma unroll
      for (int n = 0; n < 4; n++)
        acc[m][n] = __builtin_amdgcn_mfma_f32_16x16x32_bf16(afr[m], bfr[n], acc[m][n], 0, 0, 0);
    __builtin_amdgcn_s_setprio(0);
    BARRIER();

    // ---------------- phase 3: ks=1, m4-7 ----------------
    if (t + 2 < NT) SGB(cur, 0, t + 2);
    #pragma unroll
    for (int m = 0; m < 4; m++) afr[m] = *(const bx8*)&lds[cb + 8192 + aoff + (4 + m) * 512];
    BARRIER();
    __builtin_amdgcn_s_setprio(1);
    #pragma unroll
    for (int m = 0; m < 4; m++)
      #pragma unroll
      for (int n = 0; n < 4; n++)
        acc[4 + m][n] = __builtin_amdgcn_mfma_f32_16x16x32_bf16(afr[m], bfr[n], acc[4 + m][n], 0, 0, 0);
    __builtin_amdgcn_s_setprio(0);
    if (t + 2 < NT)      asm volatile("s_waitcnt vmcnt(8)" ::: "memory");
    else if (t + 1 < NT) asm volatile("s_waitcnt vmcnt(4)" ::: "memory");
    BARRIER();   // next tile's k0 ready
  }
#undef SGA
#undef SGB
#undef BARRIER

  const int row0 = bm * 256 + wm * 128 + g * 4;
  const int col0 = bn * 256 + wn * 64 + c16;
  #pragma unroll
  for (int n = 0; n < 4; n++) {
    const int col = col0 + n * 16;
    const float bb = bias[col];
    #pragma unroll
    for (int mi = 0; mi < 8; mi++) {
      #pragma unroll
      for (int r = 0; r < 4; r++) {
        float y = acc[mi][n][r] + bb;
        if (DO_GELU) {
          const float tt = y;
          y = 0.5f * tt * (1.0f + tanhf(0.7978845608f * (tt + 0.044715f * tt * tt * tt)));
        }
        const size_t idx = (size_t)(row0 + mi * 16 + r) * N + col;
        if (OUT_BF16) Cb[idx] = f2bf(y);
        else Cf[idx] = y;
      }
    }
  }
}

// ---------------- GEMM 128x128 (m97 structure) — used for N=384 final ----------------
template<int OUT_BF16, int DO_GELU>
__global__ __launch_bounds__(256, 2)
void gemm_bf16_kernel(const u16* __restrict__ A, const u16* __restrict__ Bt,
                      const float* __restrict__ bias,
                      float* __restrict__ Cf, u16* __restrict__ Cb,
                      int N, int K)
{
  __shared__ __align__(16) u16 As[128 * 32];
  __shared__ __align__(16) u16 Bs[128 * 32];
  const int tid = threadIdx.x;
  const int lane = tid & 63, wave = tid >> 6;
  const int c16 = lane & 15, g = lane >> 4;
  const int nbn = N >> 7;
  int id = blockIdx.x;
  const int nwg = gridDim.x;
  id = (id & 7) * (nwg >> 3) + (id >> 3);
  const int bm = id / nbn, bn = id % nbn;
  const int wr = wave >> 1, wc = wave & 1;

  const u16* Ab = A + (size_t)(bm * 128) * K;
  const u16* Bb = Bt + (size_t)(bn * 128) * K;

  fx4 acc[4][4] = {};

  const int ch0 = wave * 64 + lane;
  const int ch1 = 256 + ch0;

  for (int k0 = 0; k0 < K; k0 += 32) {
    gload16(Ab + (size_t)(ch0 >> 2) * K + k0 + (ch0 & 3) * 8, &As[(size_t)(wave * 64) * 8]);
    gload16(Ab + (size_t)(ch1 >> 2) * K + k0 + (ch1 & 3) * 8, &As[(size_t)(256 + wave * 64) * 8]);
    gload16(Bb + (size_t)(ch0 >> 2) * K + k0 + (ch0 & 3) * 8, &Bs[(size_t)(wave * 64) * 8]);
    gload16(Bb + (size_t)(ch1 >> 2) * K + k0 + (ch1 & 3) * 8, &Bs[(size_t)(256 + wave * 64) * 8]);
    __syncthreads();
    bx8 af[4], bf[4];
    #pragma unroll
    for (int i = 0; i < 4; i++)
      af[i] = *(const bx8*)&As[(wr * 64 + i * 16 + c16) * 32 + g * 8];
    #pragma unroll
    for (int i = 0; i < 4; i++)
      bf[i] = *(const bx8*)&Bs[(wc * 64 + i * 16 + c16) * 32 + g * 8];
    #pragma unroll
    for (int mi = 0; mi < 4; mi++)
      #pragma unroll
      for (int ni = 0; ni < 4; ni++)
        acc[mi][ni] = __builtin_amdgcn_mfma_f32_16x16x32_bf16(af[mi], bf[ni], acc[mi][ni], 0, 0, 0);
    __syncthreads();
  }

  const int row0 = bm * 128 + wr * 64 + g * 4;
  const int col0 = bn * 128 + wc * 64 + c16;
  #pragma unroll
  for (int ni = 0; ni < 4; ni++) {
    const int col = col0 + ni * 16;
    const float bb = bias[col];
    #pragma unroll
    for (int mi = 0; mi < 4; mi++) {
      #pragma unroll
      for (int r = 0; r < 4; r++) {
        float y = acc[mi][ni][r] + bb;
        if (DO_GELU) {
          const float t = y;
          y = 0.5f * t * (1.0f + tanhf(0.7978845608f * (t + 0.044715f * t * t * t)));
        }
        const size_t idx = (size_t)(row0 + mi * 16 + r) * N + col;
        if (OUT_BF16) Cb[idx] = f2bf(y);
        else Cf[idx] = y;
      }
    }
  }
}

// ---------------- Local (windowed) attention ----------------
#define V_STR 424

__global__ __launch_bounds__(512, 2)
void attn_local_kernel(const u16* __restrict__ qkv, const int* __restrict__ amask,
                       u16* __restrict__ attnout)
{
  __shared__ __align__(16) u16 Vlds[64 * V_STR];        // V^T: [d][key]
  __shared__ __align__(16) u16 Plds[8 * 16 * V_STR];    // per-wave P: [q][key]

  const int tid = threadIdx.x;
  const int lane = tid & 63, w = tid >> 6;
  const int c16 = lane & 15, g = lane >> 4;

  const int bh = blockIdx.x >> 5;
  const int n = blockIdx.x & 31;
  const int b = bh / N_HEADS, h = bh % N_HEADS;

  const u16* qkvb = qkv + (size_t)b * L_SEQ * QKV_LD + h * D_HEAD;
  const int chunk_lo = n * CHUNK - CHUNK;

  for (int idx = tid; idx < 416 * 8; idx += 512) {
    const int j = idx >> 3, d8 = (idx & 7) * 8;
    if (j >= 385) {
      #pragma unroll
      for (int i = 0; i < 8; i++) Vlds[(d8 + i) * V_STR + j] = 0;
    } else {
      int pos = (j == 384) ? 0 : chunk_lo + j;
      if (pos < 0 || pos >= L_SEQ) pos = 0;
      ux8 vv = *(const ux8*)(qkvb + (size_t)pos * QKV_LD + 2 * H_DIM + d8);
      #pragma unroll
      for (int i = 0; i < 8; i++) Vlds[(d8 + i) * V_STR + j] = vv[i];
    }
  }

  const int qrow = n * CHUNK + w * 16 + c16;
  const u16* qp = qkvb + (size_t)qrow * QKV_LD + g * 8;
  const bx8 aq0 = *(const bx8*)qp;
  const bx8 aq1 = *(const bx8*)(qp + 32);

  unsigned kvm = 0;
  #pragma unroll
  for (int kf = 0; kf < 24; kf++) {
    const int pos = chunk_lo + kf * 16 + c16;
    bool ok = (pos >= 1) && (pos < L_SEQ);
    if (ok) ok = (amask[b * L_SEQ + pos] > 0);
    kvm |= ((unsigned)ok) << kf;
  }

  fx4 s[26];
  #pragma unroll
  for (int kf = 0; kf < 25; kf++) {
    int pos = (kf == 24) ? 0 : chunk_lo + kf * 16 + c16;
    if (pos < 0 || pos >= L_SEQ) pos = 0;
    const u16* kp = qkvb + (size_t)pos * QKV_LD + H_DIM + g * 8;
    const bx8 b0 = *(const bx8*)kp;
    const bx8 b1 = *(const bx8*)(kp + 32);
    fx4 a = {};
    a = __builtin_amdgcn_mfma_f32_16x16x32_bf16(aq0, b0, a, 0, 0, 0);
    a = __builtin_amdgcn_mfma_f32_16x16x32_bf16(aq1, b1, a, 0, 0, 0);
    s[kf] = a;
  }

  const int cq = w * 16 + g * 4;
  float mx[4], sm[4];
  #pragma unroll
  for (int r = 0; r < 4; r++) mx[r] = -3.0e38f;
  #pragma unroll
  for (int kf = 0; kf < 25; kf++) {
    const int j = kf * 16 + c16;
    const bool kv = (kf < 24) ? (((kvm >> kf) & 1u) != 0) : (c16 == 0);
    #pragma unroll
    for (int r = 0; r < 4; r++) {
      const int c = cq + r;
      const bool keep = kv && (kf == 24 || (j >= c && j <= c + 256));
      const float val = keep ? s[kf][r] * 0.125f : -1.0e9f;
      s[kf][r] = val;
      mx[r] = fmaxf(mx[r], val);
    }
  }
  #pragma unroll
  for (int r = 0; r < 4; r++) {
    float m = mx[r];
    m = fmaxf(m, __shfl_xor(m, 1));
    m = fmaxf(m, __shfl_xor(m, 2));
    m = fmaxf(m, __shfl_xor(m, 4));
    m = fmaxf(m, __shfl_xor(m, 8));
    mx[r] = m;
    sm[r] = 0.f;
  }
  #pragma unroll
  for (int kf = 0; kf < 25; kf++)
    #pragma unroll
    for (int r = 0; r < 4; r++) {
      const float p = __expf(s[kf][r] - mx[r]);
      s[kf][r] = p;
      sm[r] += p;
    }
  float rinv[4];
  #pragma unroll
  for (int r = 0; r < 4; r++) {
    float t = sm[r];
    t += __shfl_xor(t, 1);
    t += __shfl_xor(t, 2);
    t += __shfl_xor(t, 4);
    t += __shfl_xor(t, 8);
    rinv[r] = 1.0f / t;
  }
  s[25] = (fx4){0.f, 0.f, 0.f, 0.f};

  u16* pb = Plds + (size_t)w * 16 * V_STR;
  #pragma unroll
  for (int kf = 0; kf < 26; kf++) {
    const int j = kf * 16 + c16;
    #pragma unroll
    for (int r = 0; r < 4; r++)
      pb[(g * 4 + r) * V_STR + j] = f2bf(s[kf][r]);
  }
  __syncthreads();

  fx4 o[4] = {};
  const u16* pr = Plds + (size_t)(w * 16 + c16) * V_STR + g * 8;
  #pragma unroll
  for (int kt = 0; kt < 13; kt++) {
    const bx8 pa = *(const bx8*)(pr + kt * 32);
    #pragma unroll
    for (int df = 0; df < 4; df++) {
      const bx8 vvf = *(const bx8*)&Vlds[(df * 16 + c16) * V_STR + kt * 32 + g * 8];
      o[df] = __builtin_amdgcn_mfma_f32_16x16x32_bf16(pa, vvf, o[df], 0, 0, 0);
    }
  }

  u16* ob = attnout + (size_t)b * L_SEQ * H_DIM + h * D_HEAD;
  const int posq = n * CHUNK + w * 16 + g * 4;
  #pragma unroll
  for (int df = 0; df < 4; df++)
    #pragma unroll
    for (int r = 0; r < 4; r++)
      ob[(size_t)(posq + r) * H_DIM + df * 16 + c16] = f2bf(o[df][r] * rinv[r]);
}

// ---------------- Global row (query position 0) ----------------
__global__ __launch_bounds__(256)
void attn_g_score(const u16* __restrict__ qkv, const int* __restrict__ amask,
                  float* __restrict__ sbuf, float* __restrict__ pmax)
{
  __shared__ float qs[D_HEAD];
  __shared__ float red[4];
  const int seg = blockIdx.x, bh = blockIdx.y;
  const int b = bh / N_HEADS, h = bh % N_HEADS;
  const u16* base = qkv + (size_t)b * L_SEQ * QKV_LD + h * D_HEAD;
  const int tid = threadIdx.x;

  if (tid < D_HEAD) qs[tid] = bf2f(base[tid]);
  __syncthreads();

  const int l = seg * 256 + tid;
  const ux8* kp = (const ux8*)(base + (size_t)l * QKV_LD + H_DIM);
  float dot = 0.f;
  #pragma unroll
  for (int i = 0; i < 8; i++) {
    const ux8 kv = kp[i];
    #pragma unroll
    for (int j = 0; j < 8; j++) dot += qs[i * 8 + j] * bf2f(kv[j]);
  }
  float sv = dot * 0.125f;
  if (amask[b * L_SEQ + l] == 0) sv = -1.0e9f;
  sbuf[(size_t)bh * L_SEQ + l] = sv;

  float m = sv;
  #pragma unroll
  for (int off = 32; off > 0; off >>= 1) m = fmaxf(m, __shfl_xor(m, off));
  if ((tid & 63) == 0) red[tid >> 6] = m;
  __syncthreads();
  if (tid == 0)
    pmax[bh * NSEG + seg] = fmaxf(fmaxf(red[0], red[1]), fmaxf(red[2], red[3]));
}

__global__ __launch_bounds__(256)
void attn_g_pv(const u16* __restrict__ qkv, const float* __restrict__ sbuf,
               const float* __restrict__ pmax, float* __restrict__ psum,
               float* __restrict__ po)
{
  __shared__ float es[256];
  __shared__ float red[4];
  const int seg = blockIdx.x, bh = blockIdx.y;
  const int b = bh / N_HEADS, h = bh % N_HEADS;
  const int tid = threadIdx.x;

  float M = -3.0e38f;
  #pragma unroll
  for (int i = 0; i < NSEG; i++) M = fmaxf(M, pmax[bh * NSEG + i]);

  const int l = seg * 256 + tid;
  const float e = __expf(sbuf[(size_t)bh * L_SEQ + l] - M);
  es[tid] = e;

  float t = e;
  #pragma unroll
  for (int off = 32; off > 0; off >>= 1) t += __shfl_xor(t, off);
  if ((tid & 63) == 0) red[tid >> 6] = t;
  __syncthreads();
  if (tid == 0) psum[bh * NSEG + seg] = red[0] + red[1] + red[2] + red[3];

  const int d = tid & 63, grp = tid >> 6;
  const u16* vb = qkv + (size_t)b * L_SEQ * QKV_LD + h * D_HEAD + 2 * H_DIM + d;
  float acc = 0.f;
  #pragma unroll 4
  for (int i = 0; i < 64; i++) {
    const int ll = seg * 256 + grp * 64 + i;
    acc += es[grp * 64 + i] * bf2f(vb[(size_t)ll * QKV_LD]);
  }
  po[(((size_t)bh * NSEG + seg) * 4 + grp) * D_HEAD + d] = acc;
}

__global__ __launch_bounds__(64)
void attn_g_combine(const float* __restrict__ psum, const float* __restrict__ po,
                    u16* __restrict__ attnout)
{
  const int bh = blockIdx.x;
  const int b = bh / N_HEADS, h = bh % N_HEADS;
  const int d = threadIdx.x;
  float S = 0.f;
  #pragma unroll
  for (int i = 0; i < NSEG; i++) S += psum[bh * NSEG + i];
  float acc = 0.f;
  #pragma unroll
  for (int i = 0; i < NSEG * 4; i++)
    acc += po[((size_t)bh * NSEG * 4 + i) * D_HEAD + d];
  attnout[(size_t)b * L_SEQ * H_DIM + h * D_HEAD + d] = f2bf(acc / S);
}

// ---------------- LayerNorm kernels ----------------
__device__ __forceinline__ void block_stats(float sum, float sq, float* red,
                                            float& mean, float& rstd)
{
  const int lane = threadIdx.x & 63, wv = threadIdx.x >> 6;
  #pragma unroll
  for (int off = 32; off > 0; off >>= 1) {
    sum += __shfl_xor(sum, off);
    sq  += __shfl_xor(sq, off);
  }
  if (lane == 0) { red[wv] = sum; red[4 + wv] = sq; }
  __syncthreads();
  sum = red[0] + red[1] + red[2] + red[3];
  sq  = red[4] + red[5] + red[6] + red[7];
  mean = sum * (1.0f / H_DIM);
  const float var = sq * (1.0f / H_DIM) - mean * mean;
  rstd = rsqrtf(var + EPS_LN);
}

__global__ __launch_bounds__(256)
void embed_ln_kernel(const int* __restrict__ ids, const float* __restrict__ wemb,
                     const float* __restrict__ pemb, const float* __restrict__ gam,
                     const float* __restrict__ bet, float* __restrict__ xf,
                     u16* __restrict__ xb)
{
  __shared__ float red[8];
  const int row = blockIdx.x, tid = threadIdx.x;
  const int l = row & (L_SEQ - 1);
  const int id = ids[row];
  float v[3]; float sum = 0.f, sq = 0.f;
  #pragma unroll
  for (int i = 0; i < 3; i++) {
    const int c = tid + i * 256;
    const float t = wemb[(size_t)id * H_DIM + c] + pemb[(size_t)l * H_DIM + c];
    v[i] = t; sum += t; sq += t * t;
  }
  float mean, rstd;
  block_stats(sum, sq, red, mean, rstd);
  #pragma unroll
  for (int i = 0; i < 3; i++) {
    const int c = tid + i * 256;
    const float y = (v[i] - mean) * rstd * gam[c] + bet[c];
    xf[(size_t)row * H_DIM + c] = y;
    xb[(size_t)row * H_DIM + c] = f2bf(y);
  }
}

__global__ __launch_bounds__(256)
void add_ln_kernel(float* xio, const float* __restrict__ yin,
                   const float* __restrict__ gam, const float* __restrict__ bet,
                   u16* __restrict__ xb)
{
  __shared__ float red[8];
  const int row = blockIdx.x, tid = threadIdx.x;
  float v[3]; float sum = 0.f, sq = 0.f;
  #pragma unroll
  for (int i = 0; i < 3; i++) {
    const int c = tid + i * 256;
    const float t = xio[(size_t)row * H_DIM + c] + yin[(size_t)row * H_DIM + c];
    v[i] = t; sum += t; sq += t * t;
  }
  float mean, rstd;
  block_stats(sum, sq, red, mean, rstd);
  #pragma unroll
  for (int i = 0; i < 3; i++) {
    const int c = tid + i * 256;
    const float y = (v[i] - mean) * rstd * gam[c] + bet[c];
    xio[(size_t)row * H_DIM + c] = y;
    xb[(size_t)row * H_DIM + c] = f2bf(y);
  }
}

// ---------------- weight transpose fp32 -> bf16 ----------------
__global__ __launch_bounds__(256)
void transpose_w_kernel(const float* __restrict__ W, u16* __restrict__ Wt, int K, int N)
{
  __shared__ float tile[32][33];
  const int k0 = blockIdx.x * 32, n0 = blockIdx.y * 32;
  const int tx = threadIdx.x & 31, ty = threadIdx.x >> 5;
  #pragma unroll
  for (int i = 0; i < 32; i += 8)
    tile[ty + i][tx] = W[(size_t)(k0 + ty + i) * N + n0 + tx];
  __syncthreads();
  #pragma unroll
  for (int i = 0; i < 32; i += 8)
    Wt[(size_t)(n0 + ty + i) * K + k0 + tx] = f2bf(tile[tx][ty + i]);
}

__global__ void concat3_kernel(const float* __restrict__ a, const float* __restrict__ b,
                               const float* __restrict__ c, float* __restrict__ out)
{
  const int i = blockIdx.x * 256 + threadIdx.x;
  if (i < H_DIM) out[i] = a[i];
  else if (i < 2 * H_DIM) out[i] = b[i - H_DIM];
  else if (i < 3 * H_DIM) out[i] = c[i - 2 * H_DIM];
}

__global__ void cls_copy_kernel(const float* __restrict__ vdn, float* __restrict__ cls)
{
  const int i = blockIdx.x * 256 + threadIdx.x;
  if (i < BATCH * OUT_DIM)
    cls[i] = vdn[(size_t)(i / OUT_DIM) * L_SEQ * OUT_DIM + (i % OUT_DIM)];
}

// ---------------- host ----------------
extern "C" void kernel_launch(void* const* d_in, const int* in_sizes, int n_in,
                              void* d_out, int out_size, void* d_ws, size_t ws_size,
                              hipStream_t stream)
{
  (void)in_sizes; (void)n_in; (void)out_size; (void)ws_size;
  const int*   ids   = (const int*)d_in[0];
  const int*   amask = (const int*)d_in[1];
  const float* wemb  = (const float*)d_in[2];
  const float* pemb  = (const float*)d_in[3];
  const float* elns  = (const float*)d_in[4];
  const float* elnb  = (const float*)d_in[5];
  const float* Wq    = (const float*)d_in[6];
  const float* bq    = (const float*)d_in[7];
  const float* Wk    = (const float*)d_in[8];
  const float* bk    = (const float*)d_in[9];
  const float* Wv    = (const float*)d_in[10];
  const float* bv    = (const float*)d_in[11];
  const float* Wo    = (const float*)d_in[12];
  const float* bo    = (const float*)d_in[13];
  const float* ln1s  = (const float*)d_in[14];
  const float* ln1b  = (const float*)d_in[15];
  const float* W1    = (const float*)d_in[16];
  const float* b1    = (const float*)d_in[17];
  const float* W2    = (const float*)d_in[18];
  const float* b2    = (const float*)d_in[19];
  const float* ln2s  = (const float*)d_in[20];
  const float* ln2b  = (const float*)d_in[21];
  const float* Wfc   = (const float*)d_in[22];
  const float* bfc   = (const float*)d_in[23];

  char* ws = (char*)d_ws;
  size_t off = 0;
  auto alloc = [&](size_t bytes) -> void* {
    void* p = ws + off;
    off += (bytes + 255) & ~(size_t)255;
    return p;
  };
  float* xf   = (float*)alloc((size_t)M_ROWS * H_DIM * 4);
  float* proj = (float*)alloc((size_t)M_ROWS * H_DIM * 4);
  u16* xb     = (u16*)alloc((size_t)M_ROWS * H_DIM * 2);
  u16* big    = (u16*)alloc((size_t)M_ROWS * FF_DIM * 2);  // qkv / ff1 time-share
  u16* attno  = (u16*)alloc((size_t)M_ROWS * H_DIM * 2);
  u16* wqkvT  = (u16*)alloc((size_t)QKV_LD * H_DIM * 2);
  u16* woT    = (u16*)alloc((size_t)H_DIM * H_DIM * 2);
  u16* w1T    = (u16*)alloc((size_t)FF_DIM * H_DIM * 2);
  u16* w2T    = (u16*)alloc((size_t)H_DIM * FF_DIM * 2);
  u16* wfcT   = (u16*)alloc((size_t)OUT_DIM * H_DIM * 2);
  float* bqkv = (float*)alloc(QKV_LD * 4);
  float* gsc  = (float*)alloc((size_t)BATCH * N_HEADS * L_SEQ * 4);
  float* gpm  = (float*)alloc((size_t)BATCH * N_HEADS * NSEG * 4);
  float* gps  = (float*)alloc((size_t)BATCH * N_HEADS * NSEG * 4);
  float* gpo  = (float*)alloc((size_t)BATCH * N_HEADS * NSEG * 4 * D_HEAD * 4);

  u16* qkvb = big;
  u16* ff1  = big;

  embed_ln_kernel<<<M_ROWS, 256, 0, stream>>>(ids, wemb, pemb, elns, elnb, xf, xb);

  for (int l = 0; l < 2; l++) {
    const size_t wof = (size_t)l * H_DIM * H_DIM;
    transpose_w_kernel<<<dim3(24, 24), 256, 0, stream>>>(Wq + wof, wqkvT, H_DIM, H_DIM);
    transpose_w_kernel<<<dim3(24, 24), 256, 0, stream>>>(Wk + wof, wqkvT + (size_t)H_DIM * H_DIM, H_DIM, H_DIM);
    transpose_w_kernel<<<dim3(24, 24), 256, 0, stream>>>(Wv + wof, wqkvT + (size_t)2 * H_DIM * H_DIM, H_DIM, H_DIM);
    transpose_w_kernel<<<dim3(24, 24), 256, 0, stream>>>(Wo + wof, woT, H_DIM, H_DIM);
    transpose_w_kernel<<<dim3(24, 96), 256, 0, stream>>>(W1 + (size_t)l * H_DIM * FF_DIM, w1T, H_DIM, FF_DIM);
    transpose_w_kernel<<<dim3(96, 24), 256, 0, stream>>>(W2 + (size_t)l * FF_DIM * H_DIM, w2T, FF_DIM, H_DIM);
    concat3_kernel<<<9, 256, 0, stream>>>(bq + l * H_DIM, bk + l * H_DIM, bv + l * H_DIM, bqkv);

    gemm256_kernel<1, 0><<<(M_ROWS / 256) * (QKV_LD / 256), 512, 0, stream>>>(
        xb, wqkvT, bqkv, nullptr, qkvb, QKV_LD, H_DIM);
    attn_local_kernel<<<BATCH * N_HEADS * N_CHUNK, 512, 0, stream>>>(qkvb, amask, attno);
    attn_g_score<<<dim3(NSEG, BATCH * N_HEADS), 256, 0, stream>>>(qkvb, amask, gsc, gpm);
    attn_g_pv<<<dim3(NSEG, BATCH * N_HEADS), 256, 0, stream>>>(qkvb, gsc, gpm, gps, gpo);
    attn_g_combine<<<BATCH * N_HEADS, 64, 0, stream>>>(gps, gpo, attno);
    gemm256_kernel<0, 0><<<(M_ROWS / 256) * (H_DIM / 256), 512, 0, stream>>>(
        attno, woT, bo + l * H_DIM, proj, nullptr, H_DIM, H_DIM);
    add_ln_kernel<<<M_ROWS, 256, 0, stream>>>(xf, proj, ln1s + l * H_DIM, ln1b + l * H_DIM, xb);
    gemm256_kernel<1, 1><<<(M_ROWS / 256) * (FF_DIM / 256), 512, 0, stream>>>(
        xb, w1T, b1 + l * FF_DIM, nullptr, ff1, FF_DIM, H_DIM);
    gemm256_kernel<0, 0><<<(M_ROWS / 256) * (H_DIM / 256), 512, 0, stream>>>(
        ff1, w2T, b2 + l * H_DIM, proj, nullptr, H_DIM, FF_DIM);
    add_ln_kernel<<<M_ROWS, 256, 0, stream>>>(xf, proj, ln2s + l * H_DIM, ln2b + l * H_DIM, xb);
  }

  transpose_w_kernel<<<dim3(24, 12), 256, 0, stream>>>(Wfc, wfcT, H_DIM, OUT_DIM);
  float* vdn = (float*)d_out;
  gemm_bf16_kernel<0, 0><<<(M_ROWS / 128) * (OUT_DIM / 128), 256, 0, stream>>>(
      xb, wfcT, bfc, vdn, nullptr, OUT_DIM, H_DIM);
  cls_copy_kernel<<<3, 256, 0, stream>>>(vdn, vdn + (size_t)BATCH * L_SEQ * OUT_DIM);
}

// Round 4
// 748.509 us; speedup vs baseline: 1.1611x; 1.1611x over previous
//
#include <hip/hip_runtime.h>
#include <hip/hip_bf16.h>
#include <stdint.h>

#define L_SEQ 4096
#define H_DIM 768
#define N_HEADS 12
#define D_HEAD 64
#define N_CHUNK 32
#define CHUNK 128
#define FF_DIM 3072
#define OUT_DIM 384
#define BATCH 2
#define EPS_LN 1e-5f
#define M_ROWS (BATCH * L_SEQ)   /* 8192 */
#define QKV_LD (3 * H_DIM)       /* 2304 */
#define NSEG 16                   /* global-row segments: 4096/256 */

typedef unsigned short u16;
typedef __bf16 bx8 __attribute__((ext_vector_type(8)));
typedef float fx4 __attribute__((ext_vector_type(4)));
typedef u16 ux8 __attribute__((ext_vector_type(8)));

__device__ __forceinline__ u16 f2bf(float f) {
  union { float f; unsigned u; } x; x.f = f;
  unsigned r = x.u + 0x7fffu + ((x.u >> 16) & 1u);
  return (u16)(r >> 16);
}
__device__ __forceinline__ float bf2f(u16 v) {
  union { unsigned u; float f; } x; x.u = ((unsigned)v) << 16;
  return x.f;
}

__device__ __forceinline__ void gload16(const void* g, void* l) {
  __builtin_amdgcn_global_load_lds((const __attribute__((address_space(1))) void*)g,
                                   (__attribute__((address_space(3))) void*)l, 16, 0, 0);
}

// =====================================================================
// 256xNTILE deep-pipelined GEMM (8 waves, BK=64, 2-deep LDS dbuf,
// counted vmcnt, setprio around MFMA). C = A @ Bt^T + bias.
//
// LDS layout per buffer: A[ks][256][32], B[ks][NTILE][32] u16, with a
// chunk swizzle: 16B chunk g of row r lives at chunk-pos g ^ ((r>>1)&3).
// Swizzle is applied on the GLOBAL source column (linear gload_lds dest,
// G21) and on the ds_read offset. Bank check: quarter-wave lanes
// c16=0..15 map to bank group 16*(c16&1) + 4*(g^((c16>>1)&3)) -> all 8
// groups x2 lanes = 2-way = free (m136).
//
// NTILE=256: waves 2x4, per-wave 128x64 (acc[8][4]), 4 phases/K-tile,
//            4 gloads/wave/K-half, steady vmcnt(8), 128 KiB LDS.
// NTILE=128: waves 4x2, per-wave 64x64 (acc[4][4]), 2 phases/K-tile,
//            3 gloads/wave/K-half, steady vmcnt(6), 96 KiB LDS.
// =====================================================================
template<int NTILE, int OUT_BF16, int DO_GELU>
__global__ __launch_bounds__(512, 2)
void gemm256_kernel(const u16* __restrict__ A, const u16* __restrict__ Bt,
                    const float* __restrict__ bias,
                    float* __restrict__ Cf, u16* __restrict__ Cb,
                    int N, int K)
{
  constexpr int BKS_B = NTILE * 32;          // u16 per ks-plane of B
  constexpr int BUFSZ = 16384 + 2 * BKS_B;   // u16 per buffer
  constexpr int MRPT = (NTILE == 256) ? 8 : 4;
  __shared__ __align__(16) u16 lds[2 * BUFSZ];

  const int tid = threadIdx.x;
  const int lane = tid & 63, w = tid >> 6;
  const int c16 = lane & 15, g = lane >> 4;
  const int wm = (NTILE == 256) ? (w >> 2) : (w >> 1);
  const int wn = (NTILE == 256) ? (w & 3) : (w & 1);
  const int arowb = wm * (16 * MRPT);

  const int nbn = N / NTILE;
  int id = blockIdx.x;
  id = (id & 7) * (gridDim.x >> 3) + (id >> 3);   // XCD swizzle (grids %8==0)
  const int bm = id / nbn, bn = id % nbn;
  const int NT = K >> 6;                          // K-tiles of 64 (NT >= 2)

  // staging source (pre-swizzled column so linear LDS dest gets permuted chunks)
  const int sw_col = ((lane & 3) ^ ((lane >> 3) & 3)) * 8;
  const int srowA = w * 32 + (lane >> 2);
  const u16* sA0 = A + (size_t)(bm * 256 + srowA) * K + sw_col;
  const u16* sA1 = sA0 + (size_t)16 * K;
  const int srowB = (NTILE == 256) ? srowA : (w * 16 + (lane >> 2));
  const u16* sB0 = Bt + (size_t)(bn * NTILE + srowB) * K + sw_col;
  const u16* sB1 = sB0 + (size_t)16 * K;   // NT256 only

#define SGA(buf, ks, t) do { const int _o = (buf)*BUFSZ + (ks)*8192 + w*1024; \
    gload16(sA0 + (size_t)(t)*64 + (ks)*32, &lds[_o]); \
    gload16(sA1 + (size_t)(t)*64 + (ks)*32, &lds[_o + 512]); } while(0)
#define SGB256(buf, ks, t) do { const int _o = (buf)*BUFSZ + 16384 + (ks)*8192 + w*1024; \
    gload16(sB0 + (size_t)(t)*64 + (ks)*32, &lds[_o]); \
    gload16(sB1 + (size_t)(t)*64 + (ks)*32, &lds[_o + 512]); } while(0)
#define SGB128(buf, ks, t) do { const int _o = (buf)*BUFSZ + 16384 + (ks)*4096 + w*512; \
    gload16(sB0 + (size_t)(t)*64 + (ks)*32, &lds[_o]); } while(0)
#define BARRIER() asm volatile("s_barrier" ::: "memory")
#define VMCNT(n)  asm volatile("s_waitcnt vmcnt(" #n ")" ::: "memory")

  fx4 acc[MRPT][4] = {};
  const int swz = (g ^ ((c16 >> 1) & 3)) * 8;
  const int aoff = (arowb + c16) * 32 + swz;            // + m*512 + ks*8192
  const int boff = 16384 + (wn * 64 + c16) * 32 + swz;  // + n*512 + ks*BKS_B

  if constexpr (NTILE == 256) {
    // prologue: t0{k0,k1} + t1{k0} = 12 loads; wait for t0k0 (8 newer in flight)
    SGA(0, 0, 0); SGB256(0, 0, 0); SGA(0, 1, 0); SGB256(0, 1, 0);
    SGA(1, 0, 1); SGB256(1, 0, 1);
    VMCNT(8);
    BARRIER();

    for (int t = 0; t < NT; ++t) {
      const int cur = t & 1, nxt = cur ^ 1;
      const int cb = cur * BUFSZ;
      bx8 afr[4], bfr[4];

      // phase 0: ks=0, m0-3
      if (t + 1 < NT) SGA(nxt, 1, t + 1);
      #pragma unroll
      for (int n = 0; n < 4; n++) bfr[n] = *(const bx8*)&lds[cb + boff + n * 512];
      #pragma unroll
      for (int m = 0; m < 4; m++) afr[m] = *(const bx8*)&lds[cb + aoff + m * 512];
      BARRIER();
      __builtin_amdgcn_s_setprio(1);
      #pragma unroll
      for (int m = 0; m < 4; m++)
        #pragma unroll
        for (int n = 0; n < 4; n++)
          acc[m][n] = __builtin_amdgcn_mfma_f32_16x16x32_bf16(afr[m], bfr[n], acc[m][n], 0, 0, 0);
      __builtin_amdgcn_s_setprio(0);
      BARRIER();

      // phase 1: ks=0, m4-7
      if (t + 1 < NT) SGB256(nxt, 1, t + 1);
      #pragma unroll
      for (int m = 0; m < 4; m++) afr[m] = *(const bx8*)&lds[cb + aoff + (4 + m) * 512];
      BARRIER();
      __builtin_amdgcn_s_setprio(1);
      #pragma unroll
      for (int m = 0; m < 4; m++)
        #pragma unroll
        for (int n = 0; n < 4; n++)
          acc[4 + m][n] = __builtin_amdgcn_mfma_f32_16x16x32_bf16(afr[m], bfr[n], acc[4 + m][n], 0, 0, 0);
      __builtin_amdgcn_s_setprio(0);
      if (t + 1 < NT) { VMCNT(8); } else { VMCNT(0); }
      BARRIER();   // k1 of cur ready

      // phase 2: ks=1, m0-3
      if (t + 2 < NT) SGA(cur, 0, t + 2);
      #pragma unroll
      for (int n = 0; n < 4; n++) bfr[n] = *(const bx8*)&lds[cb + 8192 + boff + n * 512];
      #pragma unroll
      for (int m = 0; m < 4; m++) afr[m] = *(const bx8*)&lds[cb + 8192 + aoff + m * 512];
      BARRIER();
      __builtin_amdgcn_s_setprio(1);
      #pragma unroll
      for (int m = 0; m < 4; m++)
        #pragma unroll
        for (int n = 0; n < 4; n++)
          acc[m][n] = __builtin_amdgcn_mfma_f32_16x16x32_bf16(afr[m], bfr[n], acc[m][n], 0, 0, 0);
      __builtin_amdgcn_s_setprio(0);
      BARRIER();

      // phase 3: ks=1, m4-7
      if (t + 2 < NT) SGB256(cur, 0, t + 2);
      #pragma unroll
      for (int m = 0; m < 4; m++) afr[m] = *(const bx8*)&lds[cb + 8192 + aoff + (4 + m) * 512];
      BARRIER();
      __builtin_amdgcn_s_setprio(1);
      #pragma unroll
      for (int m = 0; m < 4; m++)
        #pragma unroll
        for (int n = 0; n < 4; n++)
          acc[4 + m][n] = __builtin_amdgcn_mfma_f32_16x16x32_bf16(afr[m], bfr[n], acc[4 + m][n], 0, 0, 0);
      __builtin_amdgcn_s_setprio(0);
      if (t + 2 < NT)      { VMCNT(8); }
      else if (t + 1 < NT) { VMCNT(4); }
      BARRIER();   // next tile's k0 ready
    }
  } else {
    // NTILE=128: 3 gloads per K-half per wave; prologue 9; steady vmcnt(6)
    SGA(0, 0, 0); SGB128(0, 0, 0); SGA(0, 1, 0); SGB128(0, 1, 0);
    SGA(1, 0, 1); SGB128(1, 0, 1);
    VMCNT(6);
    BARRIER();

    for (int t = 0; t < NT; ++t) {
      const int cur = t & 1, nxt = cur ^ 1;
      const int cb = cur * BUFSZ;
      bx8 afr[4], bfr[4];

      // phase 0: ks=0
      if (t + 1 < NT) { SGA(nxt, 1, t + 1); SGB128(nxt, 1, t + 1); }
      #pragma unroll
      for (int n = 0; n < 4; n++) bfr[n] = *(const bx8*)&lds[cb + boff + n * 512];
      #pragma unroll
      for (int m = 0; m < 4; m++) afr[m] = *(const bx8*)&lds[cb + aoff + m * 512];
      BARRIER();
      __builtin_amdgcn_s_setprio(1);
      #pragma unroll
      for (int m = 0; m < 4; m++)
        #pragma unroll
        for (int n = 0; n < 4; n++)
          acc[m][n] = __builtin_amdgcn_mfma_f32_16x16x32_bf16(afr[m], bfr[n], acc[m][n], 0, 0, 0);
      __builtin_amdgcn_s_setprio(0);
      if (t + 1 < NT) { VMCNT(6); } else { VMCNT(0); }
      BARRIER();   // ks=1 of cur ready

      // phase 1: ks=1
      if (t + 2 < NT) { SGA(cur, 0, t + 2); SGB128(cur, 0, t + 2); }
      #pragma unroll
      for (int n = 0; n < 4; n++) bfr[n] = *(const bx8*)&lds[cb + boff + BKS_B + n * 512];
      #pragma unroll
      for (int m = 0; m < 4; m++) afr[m] = *(const bx8*)&lds[cb + 8192 + aoff + m * 512];
      BARRIER();
      __builtin_amdgcn_s_setprio(1);
      #pragma unroll
      for (int m = 0; m < 4; m++)
        #pragma unroll
        for (int n = 0; n < 4; n++)
          acc[m][n] = __builtin_amdgcn_mfma_f32_16x16x32_bf16(afr[m], bfr[n], acc[m][n], 0, 0, 0);
      __builtin_amdgcn_s_setprio(0);
      if (t + 2 < NT)      { VMCNT(6); }
      else if (t + 1 < NT) { VMCNT(3); }
      BARRIER();   // next tile's k0 ready
    }
  }
#undef SGA
#undef SGB256
#undef SGB128
#undef BARRIER
#undef VMCNT

  const int row0 = bm * 256 + arowb + g * 4;
  const int col0 = bn * NTILE + wn * 64 + c16;
  #pragma unroll
  for (int n = 0; n < 4; n++) {
    const int col = col0 + n * 16;
    const float bb = bias[col];
    #pragma unroll
    for (int mi = 0; mi < MRPT; mi++) {
      #pragma unroll
      for (int r = 0; r < 4; r++) {
        float y = acc[mi][n][r] + bb;
        if (DO_GELU) {
          const float tt = y;
          y = 0.5f * tt * (1.0f + tanhf(0.7978845608f * (tt + 0.044715f * tt * tt * tt)));
        }
        const size_t idx = (size_t)(row0 + mi * 16 + r) * N + col;
        if (OUT_BF16) Cb[idx] = f2bf(y);
        else Cf[idx] = y;
      }
    }
  }
}

// ---------------- GEMM 128x128 (m97 structure) — used for N=384 final ----------------
template<int OUT_BF16, int DO_GELU>
__global__ __launch_bounds__(256, 2)
void gemm_bf16_kernel(const u16* __restrict__ A, const u16* __restrict__ Bt,
                      const float* __restrict__ bias,
                      float* __restrict__ Cf, u16* __restrict__ Cb,
                      int N, int K)
{
  __shared__ __align__(16) u16 As[128 * 32];
  __shared__ __align__(16) u16 Bs[128 * 32];
  const int tid = threadIdx.x;
  const int lane = tid & 63, wave = tid >> 6;
  const int c16 = lane & 15, g = lane >> 4;
  const int nbn = N >> 7;
  int id = blockIdx.x;
  const int nwg = gridDim.x;
  id = (id & 7) * (nwg >> 3) + (id >> 3);
  const int bm = id / nbn, bn = id % nbn;
  const int wr = wave >> 1, wc = wave & 1;

  const u16* Ab = A + (size_t)(bm * 128) * K;
  const u16* Bb = Bt + (size_t)(bn * 128) * K;

  fx4 acc[4][4] = {};

  const int ch0 = wave * 64 + lane;
  const int ch1 = 256 + ch0;

  for (int k0 = 0; k0 < K; k0 += 32) {
    gload16(Ab + (size_t)(ch0 >> 2) * K + k0 + (ch0 & 3) * 8, &As[(size_t)(wave * 64) * 8]);
    gload16(Ab + (size_t)(ch1 >> 2) * K + k0 + (ch1 & 3) * 8, &As[(size_t)(256 + wave * 64) * 8]);
    gload16(Bb + (size_t)(ch0 >> 2) * K + k0 + (ch0 & 3) * 8, &Bs[(size_t)(wave * 64) * 8]);
    gload16(Bb + (size_t)(ch1 >> 2) * K + k0 + (ch1 & 3) * 8, &Bs[(size_t)(256 + wave * 64) * 8]);
    __syncthreads();
    bx8 af[4], bf[4];
    #pragma unroll
    for (int i = 0; i < 4; i++)
      af[i] = *(const bx8*)&As[(wr * 64 + i * 16 + c16) * 32 + g * 8];
    #pragma unroll
    for (int i = 0; i < 4; i++)
      bf[i] = *(const bx8*)&Bs[(wc * 64 + i * 16 + c16) * 32 + g * 8];
    #pragma unroll
    for (int mi = 0; mi < 4; mi++)
      #pragma unroll
      for (int ni = 0; ni < 4; ni++)
        acc[mi][ni] = __builtin_amdgcn_mfma_f32_16x16x32_bf16(af[mi], bf[ni], acc[mi][ni], 0, 0, 0);
    __syncthreads();
  }

  const int row0 = bm * 128 + wr * 64 + g * 4;
  const int col0 = bn * 128 + wc * 64 + c16;
  #pragma unroll
  for (int ni = 0; ni < 4; ni++) {
    const int col = col0 + ni * 16;
    const float bb = bias[col];
    #pragma unroll
    for (int mi = 0; mi < 4; mi++) {
      #pragma unroll
      for (int r = 0; r < 4; r++) {
        float y = acc[mi][ni][r] + bb;
        if (DO_GELU) {
          const float t = y;
          y = 0.5f * t * (1.0f + tanhf(0.7978845608f * (t + 0.044715f * t * t * t)));
        }
        const size_t idx = (size_t)(row0 + mi * 16 + r) * N + col;
        if (OUT_BF16) Cb[idx] = f2bf(y);
        else Cf[idx] = y;
      }
    }
  }
}

// ---------------- Local (windowed) attention ----------------
#define V_STR 424

__global__ __launch_bounds__(512, 2)
void attn_local_kernel(const u16* __restrict__ qkv, const int* __restrict__ amask,
                       u16* __restrict__ attnout)
{
  __shared__ __align__(16) u16 Vlds[64 * V_STR];        // V^T: [d][key]
  __shared__ __align__(16) u16 Plds[8 * 16 * V_STR];    // per-wave P: [q][key]

  const int tid = threadIdx.x;
  const int lane = tid & 63, w = tid >> 6;
  const int c16 = lane & 15, g = lane >> 4;

  const int bh = blockIdx.x >> 5;
  const int n = blockIdx.x & 31;
  const int b = bh / N_HEADS, h = bh % N_HEADS;

  const u16* qkvb = qkv + (size_t)b * L_SEQ * QKV_LD + h * D_HEAD;
  const int chunk_lo = n * CHUNK - CHUNK;

  for (int idx = tid; idx < 416 * 8; idx += 512) {
    const int j = idx >> 3, d8 = (idx & 7) * 8;
    if (j >= 385) {
      #pragma unroll
      for (int i = 0; i < 8; i++) Vlds[(d8 + i) * V_STR + j] = 0;
    } else {
      int pos = (j == 384) ? 0 : chunk_lo + j;
      if (pos < 0 || pos >= L_SEQ) pos = 0;
      ux8 vv = *(const ux8*)(qkvb + (size_t)pos * QKV_LD + 2 * H_DIM + d8);
      #pragma unroll
      for (int i = 0; i < 8; i++) Vlds[(d8 + i) * V_STR + j] = vv[i];
    }
  }

  const int qrow = n * CHUNK + w * 16 + c16;
  const u16* qp = qkvb + (size_t)qrow * QKV_LD + g * 8;
  const bx8 aq0 = *(const bx8*)qp;
  const bx8 aq1 = *(const bx8*)(qp + 32);

  unsigned kvm = 0;
  #pragma unroll
  for (int kf = 0; kf < 24; kf++) {
    const int pos = chunk_lo + kf * 16 + c16;
    bool ok = (pos >= 1) && (pos < L_SEQ);
    if (ok) ok = (amask[b * L_SEQ + pos] > 0);
    kvm |= ((unsigned)ok) << kf;
  }

  fx4 s[26];
  #pragma unroll
  for (int kf = 0; kf < 25; kf++) {
    int pos = (kf == 24) ? 0 : chunk_lo + kf * 16 + c16;
    if (pos < 0 || pos >= L_SEQ) pos = 0;
    const u16* kp = qkvb + (size_t)pos * QKV_LD + H_DIM + g * 8;
    const bx8 b0 = *(const bx8*)kp;
    const bx8 b1 = *(const bx8*)(kp + 32);
    fx4 a = {};
    a = __builtin_amdgcn_mfma_f32_16x16x32_bf16(aq0, b0, a, 0, 0, 0);
    a = __builtin_amdgcn_mfma_f32_16x16x32_bf16(aq1, b1, a, 0, 0, 0);
    s[kf] = a;
  }

  const int cq = w * 16 + g * 4;
  float mx[4], sm[4];
  #pragma unroll
  for (int r = 0; r < 4; r++) mx[r] = -3.0e38f;
  #pragma unroll
  for (int kf = 0; kf < 25; kf++) {
    const int j = kf * 16 + c16;
    const bool kv = (kf < 24) ? (((kvm >> kf) & 1u) != 0) : (c16 == 0);
    #pragma unroll
    for (int r = 0; r < 4; r++) {
      const int c = cq + r;
      const bool keep = kv && (kf == 24 || (j >= c && j <= c + 256));
      const float val = keep ? s[kf][r] * 0.125f : -1.0e9f;
      s[kf][r] = val;
      mx[r] = fmaxf(mx[r], val);
    }
  }
  #pragma unroll
  for (int r = 0; r < 4; r++) {
    float m = mx[r];
    m = fmaxf(m, __shfl_xor(m, 1));
    m = fmaxf(m, __shfl_xor(m, 2));
    m = fmaxf(m, __shfl_xor(m, 4));
    m = fmaxf(m, __shfl_xor(m, 8));
    mx[r] = m;
    sm[r] = 0.f;
  }
  #pragma unroll
  for (int kf = 0; kf < 25; kf++)
    #pragma unroll
    for (int r = 0; r < 4; r++) {
      const float p = __expf(s[kf][r] - mx[r]);
      s[kf][r] = p;
      sm[r] += p;
    }
  float rinv[4];
  #pragma unroll
  for (int r = 0; r < 4; r++) {
    float t = sm[r];
    t += __shfl_xor(t, 1);
    t += __shfl_xor(t, 2);
    t += __shfl_xor(t, 4);
    t += __shfl_xor(t, 8);
    rinv[r] = 1.0f / t;
  }
  s[25] = (fx4){0.f, 0.f, 0.f, 0.f};

  u16* pb = Plds + (size_t)w * 16 * V_STR;
  #pragma unroll
  for (int kf = 0; kf < 26; kf++) {
    const int j = kf * 16 + c16;
    #pragma unroll
    for (int r = 0; r < 4; r++)
      pb[(g * 4 + r) * V_STR + j] = f2bf(s[kf][r]);
  }
  __syncthreads();

  fx4 o[4] = {};
  const u16* pr = Plds + (size_t)(w * 16 + c16) * V_STR + g * 8;
  #pragma unroll
  for (int kt = 0; kt < 13; kt++) {
    const bx8 pa = *(const bx8*)(pr + kt * 32);
    #pragma unroll
    for (int df = 0; df < 4; df++) {
      const bx8 vvf = *(const bx8*)&Vlds[(df * 16 + c16) * V_STR + kt * 32 + g * 8];
      o[df] = __builtin_amdgcn_mfma_f32_16x16x32_bf16(pa, vvf, o[df], 0, 0, 0);
    }
  }

  u16* ob = attnout + (size_t)b * L_SEQ * H_DIM + h * D_HEAD;
  const int posq = n * CHUNK + w * 16 + g * 4;
  #pragma unroll
  for (int df = 0; df < 4; df++)
    #pragma unroll
    for (int r = 0; r < 4; r++)
      ob[(size_t)(posq + r) * H_DIM + df * 16 + c16] = f2bf(o[df][r] * rinv[r]);
}

// ---------------- Global row (query position 0) ----------------
__global__ __launch_bounds__(256)
void attn_g_score(const u16* __restrict__ qkv, const int* __restrict__ amask,
                  float* __restrict__ sbuf, float* __restrict__ pmax)
{
  __shared__ float qs[D_HEAD];
  __shared__ float red[4];
  const int seg = blockIdx.x, bh = blockIdx.y;
  const int b = bh / N_HEADS, h = bh % N_HEADS;
  const u16* base = qkv + (size_t)b * L_SEQ * QKV_LD + h * D_HEAD;
  const int tid = threadIdx.x;

  if (tid < D_HEAD) qs[tid] = bf2f(base[tid]);
  __syncthreads();

  const int l = seg * 256 + tid;
  const ux8* kp = (const ux8*)(base + (size_t)l * QKV_LD + H_DIM);
  float dot = 0.f;
  #pragma unroll
  for (int i = 0; i < 8; i++) {
    const ux8 kv = kp[i];
    #pragma unroll
    for (int j = 0; j < 8; j++) dot += qs[i * 8 + j] * bf2f(kv[j]);
  }
  float sv = dot * 0.125f;
  if (amask[b * L_SEQ + l] == 0) sv = -1.0e9f;
  sbuf[(size_t)bh * L_SEQ + l] = sv;

  float m = sv;
  #pragma unroll
  for (int off = 32; off > 0; off >>= 1) m = fmaxf(m, __shfl_xor(m, off));
  if ((tid & 63) == 0) red[tid >> 6] = m;
  __syncthreads();
  if (tid == 0)
    pmax[bh * NSEG + seg] = fmaxf(fmaxf(red[0], red[1]), fmaxf(red[2], red[3]));
}

__global__ __launch_bounds__(256)
void attn_g_pv(const u16* __restrict__ qkv, const float* __restrict__ sbuf,
               const float* __restrict__ pmax, float* __restrict__ psum,
               float* __restrict__ po)
{
  __shared__ float es[256];
  __shared__ float red[4];
  const int seg = blockIdx.x, bh = blockIdx.y;
  const int b = bh / N_HEADS, h = bh % N_HEADS;
  const int tid = threadIdx.x;

  float M = -3.0e38f;
  #pragma unroll
  for (int i = 0; i < NSEG; i++) M = fmaxf(M, pmax[bh * NSEG + i]);

  const int l = seg * 256 + tid;
  const float e = __expf(sbuf[(size_t)bh * L_SEQ + l] - M);
  es[tid] = e;

  float t = e;
  #pragma unroll
  for (int off = 32; off > 0; off >>= 1) t += __shfl_xor(t, off);
  if ((tid & 63) == 0) red[tid >> 6] = t;
  __syncthreads();
  if (tid == 0) psum[bh * NSEG + seg] = red[0] + red[1] + red[2] + red[3];

  const int d = tid & 63, grp = tid >> 6;
  const u16* vb = qkv + (size_t)b * L_SEQ * QKV_LD + h * D_HEAD + 2 * H_DIM + d;
  float acc = 0.f;
  #pragma unroll 4
  for (int i = 0; i < 64; i++) {
    const int ll = seg * 256 + grp * 64 + i;
    acc += es[grp * 64 + i] * bf2f(vb[(size_t)ll * QKV_LD]);
  }
  po[(((size_t)bh * NSEG + seg) * 4 + grp) * D_HEAD + d] = acc;
}

__global__ __launch_bounds__(64)
void attn_g_combine(const float* __restrict__ psum, const float* __restrict__ po,
                    u16* __restrict__ attnout)
{
  const int bh = blockIdx.x;
  const int b = bh / N_HEADS, h = bh % N_HEADS;
  const int d = threadIdx.x;
  float S = 0.f;
  #pragma unroll
  for (int i = 0; i < NSEG; i++) S += psum[bh * NSEG + i];
  float acc = 0.f;
  #pragma unroll
  for (int i = 0; i < NSEG * 4; i++)
    acc += po[((size_t)bh * NSEG * 4 + i) * D_HEAD + d];
  attnout[(size_t)b * L_SEQ * H_DIM + h * D_HEAD + d] = f2bf(acc / S);
}

// ---------------- LayerNorm kernels ----------------
__device__ __forceinline__ void block_stats(float sum, float sq, float* red,
                                            float& mean, float& rstd)
{
  const int lane = threadIdx.x & 63, wv = threadIdx.x >> 6;
  #pragma unroll
  for (int off = 32; off > 0; off >>= 1) {
    sum += __shfl_xor(sum, off);
    sq  += __shfl_xor(sq, off);
  }
  if (lane == 0) { red[wv] = sum; red[4 + wv] = sq; }
  __syncthreads();
  sum = red[0] + red[1] + red[2] + red[3];
  sq  = red[4] + red[5] + red[6] + red[7];
  mean = sum * (1.0f / H_DIM);
  const float var = sq * (1.0f / H_DIM) - mean * mean;
  rstd = rsqrtf(var + EPS_LN);
}

__global__ __launch_bounds__(256)
void embed_ln_kernel(const int* __restrict__ ids, const float* __restrict__ wemb,
                     const float* __restrict__ pemb, const float* __restrict__ gam,
                     const float* __restrict__ bet, float* __restrict__ xf,
                     u16* __restrict__ xb)
{
  __shared__ float red[8];
  const int row = blockIdx.x, tid = threadIdx.x;
  const int l = row & (L_SEQ - 1);
  const int id = ids[row];
  float v[3]; float sum = 0.f, sq = 0.f;
  #pragma unroll
  for (int i = 0; i < 3; i++) {
    const int c = tid + i * 256;
    const float t = wemb[(size_t)id * H_DIM + c] + pemb[(size_t)l * H_DIM + c];
    v[i] = t; sum += t; sq += t * t;
  }
  float mean, rstd;
  block_stats(sum, sq, red, mean, rstd);
  #pragma unroll
  for (int i = 0; i < 3; i++) {
    const int c = tid + i * 256;
    const float y = (v[i] - mean) * rstd * gam[c] + bet[c];
    xf[(size_t)row * H_DIM + c] = y;
    xb[(size_t)row * H_DIM + c] = f2bf(y);
  }
}

__global__ __launch_bounds__(256)
void add_ln_kernel(float* xio, const float* __restrict__ yin,
                   const float* __restrict__ gam, const float* __restrict__ bet,
                   u16* __restrict__ xb)
{
  __shared__ float red[8];
  const int row = blockIdx.x, tid = threadIdx.x;
  float v[3]; float sum = 0.f, sq = 0.f;
  #pragma unroll
  for (int i = 0; i < 3; i++) {
    const int c = tid + i * 256;
    const float t = xio[(size_t)row * H_DIM + c] + yin[(size_t)row * H_DIM + c];
    v[i] = t; sum += t; sq += t * t;
  }
  float mean, rstd;
  block_stats(sum, sq, red, mean, rstd);
  #pragma unroll
  for (int i = 0; i < 3; i++) {
    const int c = tid + i * 256;
    const float y = (v[i] - mean) * rstd * gam[c] + bet[c];
    xio[(size_t)row * H_DIM + c] = y;
    xb[(size_t)row * H_DIM + c] = f2bf(y);
  }
}

// ---------------- weight transpose fp32 -> bf16 ----------------
__global__ __launch_bounds__(256)
void transpose_w_kernel(const float* __restrict__ W, u16* __restrict__ Wt, int K, int N)
{
  __shared__ float tile[32][33];
  const int k0 = blockIdx.x * 32, n0 = blockIdx.y * 32;
  const int tx = threadIdx.x & 31, ty = threadIdx.x >> 5;
  #pragma unroll
  for (int i = 0; i < 32; i += 8)
    tile[ty + i][tx] = W[(size_t)(k0 + ty + i) * N + n0 + tx];
  __syncthreads();
  #pragma unroll
  for (int i = 0; i < 32; i += 8)
    Wt[(size_t)(n0 + ty + i) * K + k0 + tx] = f2bf(tile[tx][ty + i]);
}

__global__ void concat3_kernel(const float* __restrict__ a, const float* __restrict__ b,
                               const float* __restrict__ c, float* __restrict__ out)
{
  const int i = blockIdx.x * 256 + threadIdx.x;
  if (i < H_DIM) out[i] = a[i];
  else if (i < 2 * H_DIM) out[i] = b[i - H_DIM];
  else if (i < 3 * H_DIM) out[i] = c[i - 2 * H_DIM];
}

__global__ void cls_copy_kernel(const float* __restrict__ vdn, float* __restrict__ cls)
{
  const int i = blockIdx.x * 256 + threadIdx.x;
  if (i < BATCH * OUT_DIM)
    cls[i] = vdn[(size_t)(i / OUT_DIM) * L_SEQ * OUT_DIM + (i % OUT_DIM)];
}

// ---------------- host ----------------
extern "C" void kernel_launch(void* const* d_in, const int* in_sizes, int n_in,
                              void* d_out, int out_size, void* d_ws, size_t ws_size,
                              hipStream_t stream)
{
  (void)in_sizes; (void)n_in; (void)out_size; (void)ws_size;
  const int*   ids   = (const int*)d_in[0];
  const int*   amask = (const int*)d_in[1];
  const float* wemb  = (const float*)d_in[2];
  const float* pemb  = (const float*)d_in[3];
  const float* elns  = (const float*)d_in[4];
  const float* elnb  = (const float*)d_in[5];
  const float* Wq    = (const float*)d_in[6];
  const float* bq    = (const float*)d_in[7];
  const float* Wk    = (const float*)d_in[8];
  const float* bk    = (const float*)d_in[9];
  const float* Wv    = (const float*)d_in[10];
  const float* bv    = (const float*)d_in[11];
  const float* Wo    = (const float*)d_in[12];
  const float* bo    = (const float*)d_in[13];
  const float* ln1s  = (const float*)d_in[14];
  const float* ln1b  = (const float*)d_in[15];
  const float* W1    = (const float*)d_in[16];
  const float* b1    = (const float*)d_in[17];
  const float* W2    = (const float*)d_in[18];
  const float* b2    = (const float*)d_in[19];
  const float* ln2s  = (const float*)d_in[20];
  const float* ln2b  = (const float*)d_in[21];
  const float* Wfc   = (const float*)d_in[22];
  const float* bfc   = (const float*)d_in[23];

  char* ws = (char*)d_ws;
  size_t off = 0;
  auto alloc = [&](size_t bytes) -> void* {
    void* p = ws + off;
    off += (bytes + 255) & ~(size_t)255;
    return p;
  };
  float* xf   = (float*)alloc((size_t)M_ROWS * H_DIM * 4);
  float* proj = (float*)alloc((size_t)M_ROWS * H_DIM * 4);
  u16* xb     = (u16*)alloc((size_t)M_ROWS * H_DIM * 2);
  u16* big    = (u16*)alloc((size_t)M_ROWS * FF_DIM * 2);  // qkv / ff1 time-share
  u16* attno  = (u16*)alloc((size_t)M_ROWS * H_DIM * 2);
  u16* wqkvT  = (u16*)alloc((size_t)QKV_LD * H_DIM * 2);
  u16* woT    = (u16*)alloc((size_t)H_DIM * H_DIM * 2);
  u16* w1T    = (u16*)alloc((size_t)FF_DIM * H_DIM * 2);
  u16* w2T    = (u16*)alloc((size_t)H_DIM * FF_DIM * 2);
  u16* wfcT   = (u16*)alloc((size_t)OUT_DIM * H_DIM * 2);
  float* bqkv = (float*)alloc(QKV_LD * 4);
  float* gsc  = (float*)alloc((size_t)BATCH * N_HEADS * L_SEQ * 4);
  float* gpm  = (float*)alloc((size_t)BATCH * N_HEADS * NSEG * 4);
  float* gps  = (float*)alloc((size_t)BATCH * N_HEADS * NSEG * 4);
  float* gpo  = (float*)alloc((size_t)BATCH * N_HEADS * NSEG * 4 * D_HEAD * 4);

  u16* qkvb = big;
  u16* ff1  = big;

  embed_ln_kernel<<<M_ROWS, 256, 0, stream>>>(ids, wemb, pemb, elns, elnb, xf, xb);

  for (int l = 0; l < 2; l++) {
    const size_t wof = (size_t)l * H_DIM * H_DIM;
    transpose_w_kernel<<<dim3(24, 24), 256, 0, stream>>>(Wq + wof, wqkvT, H_DIM, H_DIM);
    transpose_w_kernel<<<dim3(24, 24), 256, 0, stream>>>(Wk + wof, wqkvT + (size_t)H_DIM * H_DIM, H_DIM, H_DIM);
    transpose_w_kernel<<<dim3(24, 24), 256, 0, stream>>>(Wv + wof, wqkvT + (size_t)2 * H_DIM * H_DIM, H_DIM, H_DIM);
    transpose_w_kernel<<<dim3(24, 24), 256, 0, stream>>>(Wo + wof, woT, H_DIM, H_DIM);
    transpose_w_kernel<<<dim3(24, 96), 256, 0, stream>>>(W1 + (size_t)l * H_DIM * FF_DIM, w1T, H_DIM, FF_DIM);
    transpose_w_kernel<<<dim3(96, 24), 256, 0, stream>>>(W2 + (size_t)l * FF_DIM * H_DIM, w2T, FF_DIM, H_DIM);
    concat3_kernel<<<9, 256, 0, stream>>>(bq + l * H_DIM, bk + l * H_DIM, bv + l * H_DIM, bqkv);

    gemm256_kernel<256, 1, 0><<<(M_ROWS / 256) * (QKV_LD / 256), 512, 0, stream>>>(
        xb, wqkvT, bqkv, nullptr, qkvb, QKV_LD, H_DIM);
    attn_local_kernel<<<BATCH * N_HEADS * N_CHUNK, 512, 0, stream>>>(qkvb, amask, attno);
    attn_g_score<<<dim3(NSEG, BATCH * N_HEADS), 256, 0, stream>>>(qkvb, amask, gsc, gpm);
    attn_g_pv<<<dim3(NSEG, BATCH * N_HEADS), 256, 0, stream>>>(qkvb, gsc, gpm, gps, gpo);
    attn_g_combine<<<BATCH * N_HEADS, 64, 0, stream>>>(gps, gpo, attno);
    gemm256_kernel<128, 0, 0><<<(M_ROWS / 256) * (H_DIM / 128), 512, 0, stream>>>(
        attno, woT, bo + l * H_DIM, proj, nullptr, H_DIM, H_DIM);
    add_ln_kernel<<<M_ROWS, 256, 0, stream>>>(xf, proj, ln1s + l * H_DIM, ln1b + l * H_DIM, xb);
    gemm256_kernel<256, 1, 1><<<(M_ROWS / 256) * (FF_DIM / 256), 512, 0, stream>>>(
        xb, w1T, b1 + l * FF_DIM, nullptr, ff1, FF_DIM, H_DIM);
    gemm256_kernel<128, 0, 0><<<(M_ROWS / 256) * (H_DIM / 128), 512, 0, stream>>>(
        ff1, w2T, b2 + l * H_DIM, proj, nullptr, H_DIM, FF_DIM);
    add_ln_kernel<<<M_ROWS, 256, 0, stream>>>(xf, proj, ln2s + l * H_DIM, ln2b + l * H_DIM, xb);
  }

  transpose_w_kernel<<<dim3(24, 12), 256, 0, stream>>>(Wfc, wfcT, H_DIM, OUT_DIM);
  float* vdn = (float*)d_out;
  gemm_bf16_kernel<0, 0><<<(M_ROWS / 128) * (OUT_DIM / 128), 256, 0, stream>>>(
      xb, wfcT, bfc, vdn, nullptr, OUT_DIM, H_DIM);
  cls_copy_kernel<<<3, 256, 0, stream>>>(vdn, vdn + (size_t)BATCH * L_SEQ * OUT_DIM);
}

// Round 5
// 722.568 us; speedup vs baseline: 1.2028x; 1.0359x over previous
//
#include <hip/hip_runtime.h>
#include <hip/hip_bf16.h>
#include <stdint.h>

#define L_SEQ 4096
#define H_DIM 768
#define N_HEADS 12
#define D_HEAD 64
#define N_CHUNK 32
#define CHUNK 128
#define FF_DIM 3072
#define OUT_DIM 384
#define BATCH 2
#define EPS_LN 1e-5f
#define M_ROWS (BATCH * L_SEQ)   /* 8192 */
#define QKV_LD (3 * H_DIM)       /* 2304 */
#define NSEG 16                   /* global-row segments: 4096/256 */

typedef unsigned short u16;
typedef __bf16 bx8 __attribute__((ext_vector_type(8)));
typedef float fx4 __attribute__((ext_vector_type(4)));
typedef u16 ux8 __attribute__((ext_vector_type(8)));

__device__ __forceinline__ u16 f2bf(float f) {
  union { float f; unsigned u; } x; x.f = f;
  unsigned r = x.u + 0x7fffu + ((x.u >> 16) & 1u);
  return (u16)(r >> 16);
}
__device__ __forceinline__ float bf2f(u16 v) {
  union { unsigned u; float f; } x; x.u = ((unsigned)v) << 16;
  return x.f;
}

__device__ __forceinline__ void gload16(const void* g, void* l) {
  __builtin_amdgcn_global_load_lds((const __attribute__((address_space(1))) void*)g,
                                   (__attribute__((address_space(3))) void*)l, 16, 0, 0);
}

// =====================================================================
// Pipelined GEMM, 3-slot rotating half-tile LDS (all offsets compile-time).
// C(M x N) = A(MxK) @ Bt(NxK)^T + bias.  BK=64, half-tile = one ks (32 k).
// Half-tile (t,ks) lives in slot (2t+ks) % 3  (A and B separately).
//   NTILE=256: 8 waves (2x4), per-wave 128x64, acc[8][4], 4 phases/tile,
//              LDS 3*(16K+16K)=96 KiB, 1 block/CU.
//   NTILE=128: 4 waves (2x2), per-wave 64x64, acc[4][4], 2 phases/tile,
//              LDS 3*(8K+8K)=48 KiB, 3 blocks/CU (TLP covers stalls).
// Stage schedule (tile t stages tile t+1, one half-tile matrix per phase):
//   slot of (t+1,0) = (2t+2)%3: occupant (t-1,1), reads done in t-1 -> free.
//   slot of (t+1,1) = (2t)%3  = s0(t): reads done by end ph1 (ph0/ph1 MFMA
//   consumed them before the barrier) -> staged in ph2/ph3 (256) / ph1 (128).
// vmcnt ledger (per wave): 256: 2 loads/stage-op, 8/tile; steady VMCNT(4)
//   at ph1-end (retires (t,1), issued t-1 ph2-3) and ph3-end (retires
//   (t+1,0), issued t ph0-1). 128: 4 loads/phase; VMCNT(4) at each phase
//   end. Last tile: VMCNT(0) before its ks1 reads, no staging.
// Swizzle (refcheck'd r4, conflicts=0): global src col pre-swizzled
//   ((lane&3)^((lane>>3)&3))*8; read offset (g^((c16>>1)&3))*8.
// =====================================================================
template<int NTILE, int OUT_BF16, int DO_GELU>
__global__ __launch_bounds__((NTILE == 256) ? 512 : 256, (NTILE == 256) ? 2 : 3)
void gemm_p(const u16* __restrict__ A, const u16* __restrict__ Bt,
            const float* __restrict__ bias,
            float* __restrict__ Cf, u16* __restrict__ Cb,
            int N, int K)
{
  constexpr int BM    = (NTILE == 256) ? 256 : 128;
  constexpr int MRPT  = (NTILE == 256) ? 8 : 4;
  constexpr int ASLOT = BM * 32;        // u16 per A half-tile
  constexpr int BSLOT = NTILE * 32;     // u16 per B half-tile
  constexpr int BBASE = 3 * ASLOT;
  __shared__ __align__(16) u16 lds[3 * ASLOT + 3 * BSLOT];

  const int tid = threadIdx.x;
  const int lane = tid & 63, w = tid >> 6;
  const int c16 = lane & 15, g = lane >> 4;
  const int wm = (NTILE == 256) ? (w >> 2) : (w >> 1);
  const int wn = (NTILE == 256) ? (w & 3) : (w & 1);
  const int arowb = wm * (16 * MRPT);

  const int nbn = N / NTILE;
  int id = blockIdx.x;
  id = (id & 7) * (gridDim.x >> 3) + (id >> 3);   // XCD swizzle (grids %8==0)
  const int bm = id / nbn, bn = id % nbn;
  const int NT = K >> 6;                          // K-tiles of 64; NT%3==0, NT>=6

  // staging: each thread 2 chunks of 16B for A-half and for B-half
  const int sw_col = ((lane & 3) ^ ((lane >> 3) & 3)) * 8;
  const int srow = w * 32 + (lane >> 2);
  const u16* sA0 = A + (size_t)(bm * BM + srow) * K + sw_col;
  const u16* sA1 = sA0 + (size_t)16 * K;
  const u16* sB0 = Bt + (size_t)(bn * NTILE + srow) * K + sw_col;
  const u16* sB1 = sB0 + (size_t)16 * K;
  const int wdst = w * 1024;   // wave-uniform LDS dst (u16)

#define SGA(slot, kc) do { \
    gload16(sA0 + (kc), &lds[(slot) * ASLOT + wdst]); \
    gload16(sA1 + (kc), &lds[(slot) * ASLOT + wdst + 512]); } while (0)
#define SGB(slot, kc) do { \
    gload16(sB0 + (kc), &lds[BBASE + (slot) * BSLOT + wdst]); \
    gload16(sB1 + (kc), &lds[BBASE + (slot) * BSLOT + wdst + 512]); } while (0)
#define BAR() asm volatile("s_barrier" ::: "memory")
#define VM4() asm volatile("s_waitcnt vmcnt(4)" ::: "memory")
#define VM0() asm volatile("s_waitcnt vmcnt(0)" ::: "memory")

  fx4 acc[MRPT][4] = {};
  const int swz = (g ^ ((c16 >> 1) & 3)) * 8;
  const int aoff = (arowb + c16) * 32 + swz;   // + m*512 + slot*ASLOT
  const int boff = (wn * 64 + c16) * 32 + swz; // + n*512 + BBASE + slot*BSLOT

  // ---- prologue: stage (0,0)->slot0, (0,1)->slot1; wait (0,0) ----
  SGA(0, 0); SGB(0, 0); SGA(1, 32); SGB(1, 32);
  VM4();
  BAR();

  int kc = 64;   // source col for tile t+1, advances 64/tile

  if constexpr (NTILE == 256) {
    auto tile = [&](int s0, int s1, int sp0, bool stage, bool last)
        __attribute__((always_inline)) {
      bx8 afr[4], bfr[4];
      // ph0: ks0, m0-3
      if (stage) SGA(sp0, kc);
      #pragma unroll
      for (int n = 0; n < 4; n++) bfr[n] = *(const bx8*)&lds[BBASE + s0 * BSLOT + boff + n * 512];
      #pragma unroll
      for (int m = 0; m < 4; m++) afr[m] = *(const bx8*)&lds[s0 * ASLOT + aoff + m * 512];
      BAR();
      __builtin_amdgcn_s_setprio(1);
      #pragma unroll
      for (int m = 0; m < 4; m++)
        #pragma unroll
        for (int n = 0; n < 4; n++)
          acc[m][n] = __builtin_amdgcn_mfma_f32_16x16x32_bf16(afr[m], bfr[n], acc[m][n], 0, 0, 0);
      __builtin_amdgcn_s_setprio(0);
      BAR();
      // ph1: ks0, m4-7
      if (stage) SGB(sp0, kc);
      #pragma unroll
      for (int m = 0; m < 4; m++) afr[m] = *(const bx8*)&lds[s0 * ASLOT + aoff + (4 + m) * 512];
      BAR();
      __builtin_amdgcn_s_setprio(1);
      #pragma unroll
      for (int m = 0; m < 4; m++)
        #pragma unroll
        for (int n = 0; n < 4; n++)
          acc[4 + m][n] = __builtin_amdgcn_mfma_f32_16x16x32_bf16(afr[m], bfr[n], acc[4 + m][n], 0, 0, 0);
      __builtin_amdgcn_s_setprio(0);
      if (last) { VM0(); } else { VM4(); }   // (t,1) ready
      BAR();
      // ph2: ks1, m0-3   (stage (t+1,1) -> s0: its reads finished ph0/ph1)
      if (stage) SGA(s0, kc + 32);
      #pragma unroll
      for (int n = 0; n < 4; n++) bfr[n] = *(const bx8*)&lds[BBASE + s1 * BSLOT + boff + n * 512];
      #pragma unroll
      for (int m = 0; m < 4; m++) afr[m] = *(const bx8*)&lds[s1 * ASLOT + aoff + m * 512];
      BAR();
      __builtin_amdgcn_s_setprio(1);
      #pragma unroll
      for (int m = 0; m < 4; m++)
        #pragma unroll
        for (int n = 0; n < 4; n++)
          acc[m][n] = __builtin_amdgcn_mfma_f32_16x16x32_bf16(afr[m], bfr[n], acc[m][n], 0, 0, 0);
      __builtin_amdgcn_s_setprio(0);
      BAR();
      // ph3: ks1, m4-7
      if (stage) SGB(s0, kc + 32);
      #pragma unroll
      for (int m = 0; m < 4; m++) afr[m] = *(const bx8*)&lds[s1 * ASLOT + aoff + (4 + m) * 512];
      BAR();
      __builtin_amdgcn_s_setprio(1);
      #pragma unroll
      for (int m = 0; m < 4; m++)
        #pragma unroll
        for (int n = 0; n < 4; n++)
          acc[4 + m][n] = __builtin_amdgcn_mfma_f32_16x16x32_bf16(afr[m], bfr[n], acc[4 + m][n], 0, 0, 0);
      __builtin_amdgcn_s_setprio(0);
      if (!last) VM4();                      // (t+1,0) ready
      BAR();
      kc += 64;
    };
    for (int i = 0; i < NT / 3 - 1; ++i) {
      tile(0, 1, 2, true, false);
      tile(2, 0, 1, true, false);
      tile(1, 2, 0, true, false);
    }
    tile(0, 1, 2, true, false);
    tile(2, 0, 1, true, false);
    tile(1, 2, 0, false, true);
  } else {
    auto tile = [&](int s0, int s1, int sp0, bool stage, bool last)
        __attribute__((always_inline)) {
      bx8 afr[4], bfr[4];
      // ph0: ks0 (all m)
      if (stage) { SGA(sp0, kc); SGB(sp0, kc); }
      #pragma unroll
      for (int n = 0; n < 4; n++) bfr[n] = *(const bx8*)&lds[BBASE + s0 * BSLOT + boff + n * 512];
      #pragma unroll
      for (int m = 0; m < 4; m++) afr[m] = *(const bx8*)&lds[s0 * ASLOT + aoff + m * 512];
      BAR();
      __builtin_amdgcn_s_setprio(1);
      #pragma unroll
      for (int m = 0; m < 4; m++)
        #pragma unroll
        for (int n = 0; n < 4; n++)
          acc[m][n] = __builtin_amdgcn_mfma_f32_16x16x32_bf16(afr[m], bfr[n], acc[m][n], 0, 0, 0);
      __builtin_amdgcn_s_setprio(0);
      if (last) { VM0(); } else { VM4(); }   // (t,1) ready
      BAR();
      // ph1: ks1  (stage (t+1,1) -> s0)
      if (stage) { SGA(s0, kc + 32); SGB(s0, kc + 32); }
      #pragma unroll
      for (int n = 0; n < 4; n++) bfr[n] = *(const bx8*)&lds[BBASE + s1 * BSLOT + boff + n * 512];
      #pragma unroll
      for (int m = 0; m < 4; m++) afr[m] = *(const bx8*)&lds[s1 * ASLOT + aoff + m * 512];
      BAR();
      __builtin_amdgcn_s_setprio(1);
      #pragma unroll
      for (int m = 0; m < 4; m++)
        #pragma unroll
        for (int n = 0; n < 4; n++)
          acc[m][n] = __builtin_amdgcn_mfma_f32_16x16x32_bf16(afr[m], bfr[n], acc[m][n], 0, 0, 0);
      __builtin_amdgcn_s_setprio(0);
      if (!last) VM4();                      // (t+1,0) ready
      BAR();
      kc += 64;
    };
    for (int i = 0; i < NT / 3 - 1; ++i) {
      tile(0, 1, 2, true, false);
      tile(2, 0, 1, true, false);
      tile(1, 2, 0, true, false);
    }
    tile(0, 1, 2, true, false);
    tile(2, 0, 1, true, false);
    tile(1, 2, 0, false, true);
  }
#undef SGA
#undef SGB
#undef BAR
#undef VM4
#undef VM0

  const int row0 = bm * BM + arowb + g * 4;
  const int col0 = bn * NTILE + wn * 64 + c16;
  #pragma unroll
  for (int n = 0; n < 4; n++) {
    const int col = col0 + n * 16;
    const float bb = bias[col];
    #pragma unroll
    for (int mi = 0; mi < MRPT; mi++) {
      #pragma unroll
      for (int r = 0; r < 4; r++) {
        float y = acc[mi][n][r] + bb;
        if (DO_GELU) {
          const float tt = y;
          y = 0.5f * tt * (1.0f + tanhf(0.7978845608f * (tt + 0.044715f * tt * tt * tt)));
        }
        const size_t idx = (size_t)(row0 + mi * 16 + r) * N + col;
        if (OUT_BF16) Cb[idx] = f2bf(y);
        else Cf[idx] = y;
      }
    }
  }
}

// ---------------- Local (windowed) attention ----------------
#define V_STR 424

__global__ __launch_bounds__(512, 2)
void attn_local_kernel(const u16* __restrict__ qkv, const int* __restrict__ amask,
                       u16* __restrict__ attnout)
{
  __shared__ __align__(16) u16 Vlds[64 * V_STR];        // V^T: [d][key]
  __shared__ __align__(16) u16 Plds[8 * 16 * V_STR];    // per-wave P: [q][key]

  const int tid = threadIdx.x;
  const int lane = tid & 63, w = tid >> 6;
  const int c16 = lane & 15, g = lane >> 4;

  const int bh = blockIdx.x >> 5;
  const int n = blockIdx.x & 31;
  const int b = bh / N_HEADS, h = bh % N_HEADS;

  const u16* qkvb = qkv + (size_t)b * L_SEQ * QKV_LD + h * D_HEAD;
  const int chunk_lo = n * CHUNK - CHUNK;

  for (int idx = tid; idx < 416 * 8; idx += 512) {
    const int j = idx >> 3, d8 = (idx & 7) * 8;
    if (j >= 385) {
      #pragma unroll
      for (int i = 0; i < 8; i++) Vlds[(d8 + i) * V_STR + j] = 0;
    } else {
      int pos = (j == 384) ? 0 : chunk_lo + j;
      if (pos < 0 || pos >= L_SEQ) pos = 0;
      ux8 vv = *(const ux8*)(qkvb + (size_t)pos * QKV_LD + 2 * H_DIM + d8);
      #pragma unroll
      for (int i = 0; i < 8; i++) Vlds[(d8 + i) * V_STR + j] = vv[i];
    }
  }

  const int qrow = n * CHUNK + w * 16 + c16;
  const u16* qp = qkvb + (size_t)qrow * QKV_LD + g * 8;
  const bx8 aq0 = *(const bx8*)qp;
  const bx8 aq1 = *(const bx8*)(qp + 32);

  unsigned kvm = 0;
  #pragma unroll
  for (int kf = 0; kf < 24; kf++) {
    const int pos = chunk_lo + kf * 16 + c16;
    bool ok = (pos >= 1) && (pos < L_SEQ);
    if (ok) ok = (amask[b * L_SEQ + pos] > 0);
    kvm |= ((unsigned)ok) << kf;
  }

  fx4 s[26];
  #pragma unroll
  for (int kf = 0; kf < 25; kf++) {
    int pos = (kf == 24) ? 0 : chunk_lo + kf * 16 + c16;
    if (pos < 0 || pos >= L_SEQ) pos = 0;
    const u16* kp = qkvb + (size_t)pos * QKV_LD + H_DIM + g * 8;
    const bx8 b0 = *(const bx8*)kp;
    const bx8 b1 = *(const bx8*)(kp + 32);
    fx4 a = {};
    a = __builtin_amdgcn_mfma_f32_16x16x32_bf16(aq0, b0, a, 0, 0, 0);
    a = __builtin_amdgcn_mfma_f32_16x16x32_bf16(aq1, b1, a, 0, 0, 0);
    s[kf] = a;
  }

  const int cq = w * 16 + g * 4;
  float mx[4], sm[4];
  #pragma unroll
  for (int r = 0; r < 4; r++) mx[r] = -3.0e38f;
  #pragma unroll
  for (int kf = 0; kf < 25; kf++) {
    const int j = kf * 16 + c16;
    const bool kv = (kf < 24) ? (((kvm >> kf) & 1u) != 0) : (c16 == 0);
    #pragma unroll
    for (int r = 0; r < 4; r++) {
      const int c = cq + r;
      const bool keep = kv && (kf == 24 || (j >= c && j <= c + 256));
      const float val = keep ? s[kf][r] * 0.125f : -1.0e9f;
      s[kf][r] = val;
      mx[r] = fmaxf(mx[r], val);
    }
  }
  #pragma unroll
  for (int r = 0; r < 4; r++) {
    float m = mx[r];
    m = fmaxf(m, __shfl_xor(m, 1));
    m = fmaxf(m, __shfl_xor(m, 2));
    m = fmaxf(m, __shfl_xor(m, 4));
    m = fmaxf(m, __shfl_xor(m, 8));
    mx[r] = m;
    sm[r] = 0.f;
  }
  #pragma unroll
  for (int kf = 0; kf < 25; kf++)
    #pragma unroll
    for (int r = 0; r < 4; r++) {
      const float p = __expf(s[kf][r] - mx[r]);
      s[kf][r] = p;
      sm[r] += p;
    }
  float rinv[4];
  #pragma unroll
  for (int r = 0; r < 4; r++) {
    float t = sm[r];
    t += __shfl_xor(t, 1);
    t += __shfl_xor(t, 2);
    t += __shfl_xor(t, 4);
    t += __shfl_xor(t, 8);
    rinv[r] = 1.0f / t;
  }
  s[25] = (fx4){0.f, 0.f, 0.f, 0.f};

  u16* pb = Plds + (size_t)w * 16 * V_STR;
  #pragma unroll
  for (int kf = 0; kf < 26; kf++) {
    const int j = kf * 16 + c16;
    #pragma unroll
    for (int r = 0; r < 4; r++)
      pb[(g * 4 + r) * V_STR + j] = f2bf(s[kf][r]);
  }
  __syncthreads();

  fx4 o[4] = {};
  const u16* pr = Plds + (size_t)(w * 16 + c16) * V_STR + g * 8;
  #pragma unroll
  for (int kt = 0; kt < 13; kt++) {
    const bx8 pa = *(const bx8*)(pr + kt * 32);
    #pragma unroll
    for (int df = 0; df < 4; df++) {
      const bx8 vvf = *(const bx8*)&Vlds[(df * 16 + c16) * V_STR + kt * 32 + g * 8];
      o[df] = __builtin_amdgcn_mfma_f32_16x16x32_bf16(pa, vvf, o[df], 0, 0, 0);
    }
  }

  u16* ob = attnout + (size_t)b * L_SEQ * H_DIM + h * D_HEAD;
  const int posq = n * CHUNK + w * 16 + g * 4;
  #pragma unroll
  for (int df = 0; df < 4; df++)
    #pragma unroll
    for (int r = 0; r < 4; r++)
      ob[(size_t)(posq + r) * H_DIM + df * 16 + c16] = f2bf(o[df][r] * rinv[r]);
}

// ---------------- Global row (query position 0) ----------------
__global__ __launch_bounds__(256)
void attn_g_score(const u16* __restrict__ qkv, const int* __restrict__ amask,
                  float* __restrict__ sbuf, float* __restrict__ pmax)
{
  __shared__ float qs[D_HEAD];
  __shared__ float red[4];
  const int seg = blockIdx.x, bh = blockIdx.y;
  const int b = bh / N_HEADS, h = bh % N_HEADS;
  const u16* base = qkv + (size_t)b * L_SEQ * QKV_LD + h * D_HEAD;
  const int tid = threadIdx.x;

  if (tid < D_HEAD) qs[tid] = bf2f(base[tid]);
  __syncthreads();

  const int l = seg * 256 + tid;
  const ux8* kp = (const ux8*)(base + (size_t)l * QKV_LD + H_DIM);
  float dot = 0.f;
  #pragma unroll
  for (int i = 0; i < 8; i++) {
    const ux8 kv = kp[i];
    #pragma unroll
    for (int j = 0; j < 8; j++) dot += qs[i * 8 + j] * bf2f(kv[j]);
  }
  float sv = dot * 0.125f;
  if (amask[b * L_SEQ + l] == 0) sv = -1.0e9f;
  sbuf[(size_t)bh * L_SEQ + l] = sv;

  float m = sv;
  #pragma unroll
  for (int off = 32; off > 0; off >>= 1) m = fmaxf(m, __shfl_xor(m, off));
  if ((tid & 63) == 0) red[tid >> 6] = m;
  __syncthreads();
  if (tid == 0)
    pmax[bh * NSEG + seg] = fmaxf(fmaxf(red[0], red[1]), fmaxf(red[2], red[3]));
}

__global__ __launch_bounds__(256)
void attn_g_pv(const u16* __restrict__ qkv, const float* __restrict__ sbuf,
               const float* __restrict__ pmax, float* __restrict__ psum,
               float* __restrict__ po)
{
  __shared__ float es[256];
  __shared__ float red[4];
  const int seg = blockIdx.x, bh = blockIdx.y;
  const int b = bh / N_HEADS, h = bh % N_HEADS;
  const int tid = threadIdx.x;

  float M = -3.0e38f;
  #pragma unroll
  for (int i = 0; i < NSEG; i++) M = fmaxf(M, pmax[bh * NSEG + i]);

  const int l = seg * 256 + tid;
  const float e = __expf(sbuf[(size_t)bh * L_SEQ + l] - M);
  es[tid] = e;

  float t = e;
  #pragma unroll
  for (int off = 32; off > 0; off >>= 1) t += __shfl_xor(t, off);
  if ((tid & 63) == 0) red[tid >> 6] = t;
  __syncthreads();
  if (tid == 0) psum[bh * NSEG + seg] = red[0] + red[1] + red[2] + red[3];

  const int d = tid & 63, grp = tid >> 6;
  const u16* vb = qkv + (size_t)b * L_SEQ * QKV_LD + h * D_HEAD + 2 * H_DIM + d;
  float acc = 0.f;
  #pragma unroll 4
  for (int i = 0; i < 64; i++) {
    const int ll = seg * 256 + grp * 64 + i;
    acc += es[grp * 64 + i] * bf2f(vb[(size_t)ll * QKV_LD]);
  }
  po[(((size_t)bh * NSEG + seg) * 4 + grp) * D_HEAD + d] = acc;
}

__global__ __launch_bounds__(64)
void attn_g_combine(const float* __restrict__ psum, const float* __restrict__ po,
                    u16* __restrict__ attnout)
{
  const int bh = blockIdx.x;
  const int b = bh / N_HEADS, h = bh % N_HEADS;
  const int d = threadIdx.x;
  float S = 0.f;
  #pragma unroll
  for (int i = 0; i < NSEG; i++) S += psum[bh * NSEG + i];
  float acc = 0.f;
  #pragma unroll
  for (int i = 0; i < NSEG * 4; i++)
    acc += po[((size_t)bh * NSEG * 4 + i) * D_HEAD + d];
  attnout[(size_t)b * L_SEQ * H_DIM + h * D_HEAD + d] = f2bf(acc / S);
}

// ---------------- LayerNorm kernels ----------------
__device__ __forceinline__ void block_stats(float sum, float sq, float* red,
                                            float& mean, float& rstd)
{
  const int lane = threadIdx.x & 63, wv = threadIdx.x >> 6;
  #pragma unroll
  for (int off = 32; off > 0; off >>= 1) {
    sum += __shfl_xor(sum, off);
    sq  += __shfl_xor(sq, off);
  }
  if (lane == 0) { red[wv] = sum; red[4 + wv] = sq; }
  __syncthreads();
  sum = red[0] + red[1] + red[2] + red[3];
  sq  = red[4] + red[5] + red[6] + red[7];
  mean = sum * (1.0f / H_DIM);
  const float var = sq * (1.0f / H_DIM) - mean * mean;
  rstd = rsqrtf(var + EPS_LN);
}

__global__ __launch_bounds__(256)
void embed_ln_kernel(const int* __restrict__ ids, const float* __restrict__ wemb,
                     const float* __restrict__ pemb, const float* __restrict__ gam,
                     const float* __restrict__ bet, float* __restrict__ xf,
                     u16* __restrict__ xb)
{
  __shared__ float red[8];
  const int row = blockIdx.x, tid = threadIdx.x;
  const int l = row & (L_SEQ - 1);
  const int id = ids[row];
  float v[3]; float sum = 0.f, sq = 0.f;
  #pragma unroll
  for (int i = 0; i < 3; i++) {
    const int c = tid + i * 256;
    const float t = wemb[(size_t)id * H_DIM + c] + pemb[(size_t)l * H_DIM + c];
    v[i] = t; sum += t; sq += t * t;
  }
  float mean, rstd;
  block_stats(sum, sq, red, mean, rstd);
  #pragma unroll
  for (int i = 0; i < 3; i++) {
    const int c = tid + i * 256;
    const float y = (v[i] - mean) * rstd * gam[c] + bet[c];
    xf[(size_t)row * H_DIM + c] = y;
    xb[(size_t)row * H_DIM + c] = f2bf(y);
  }
}

__global__ __launch_bounds__(256)
void add_ln_kernel(float* xio, const float* __restrict__ yin,
                   const float* __restrict__ gam, const float* __restrict__ bet,
                   u16* __restrict__ xb)
{
  __shared__ float red[8];
  const int row = blockIdx.x, tid = threadIdx.x;
  float v[3]; float sum = 0.f, sq = 0.f;
  #pragma unroll
  for (int i = 0; i < 3; i++) {
    const int c = tid + i * 256;
    const float t = xio[(size_t)row * H_DIM + c] + yin[(size_t)row * H_DIM + c];
    v[i] = t; sum += t; sq += t * t;
  }
  float mean, rstd;
  block_stats(sum, sq, red, mean, rstd);
  #pragma unroll
  for (int i = 0; i < 3; i++) {
    const int c = tid + i * 256;
    const float y = (v[i] - mean) * rstd * gam[c] + bet[c];
    xio[(size_t)row * H_DIM + c] = y;
    xb[(size_t)row * H_DIM + c] = f2bf(y);
  }
}

// ---------------- weight transpose fp32 -> bf16 ----------------
__global__ __launch_bounds__(256)
void transpose_w_kernel(const float* __restrict__ W, u16* __restrict__ Wt, int K, int N)
{
  __shared__ float tile[32][33];
  const int k0 = blockIdx.x * 32, n0 = blockIdx.y * 32;
  const int tx = threadIdx.x & 31, ty = threadIdx.x >> 5;
  #pragma unroll
  for (int i = 0; i < 32; i += 8)
    tile[ty + i][tx] = W[(size_t)(k0 + ty + i) * N + n0 + tx];
  __syncthreads();
  #pragma unroll
  for (int i = 0; i < 32; i += 8)
    Wt[(size_t)(n0 + ty + i) * K + k0 + tx] = f2bf(tile[tx][ty + i]);
}

__global__ void concat3_kernel(const float* __restrict__ a, const float* __restrict__ b,
                               const float* __restrict__ c, float* __restrict__ out)
{
  const int i = blockIdx.x * 256 + threadIdx.x;
  if (i < H_DIM) out[i] = a[i];
  else if (i < 2 * H_DIM) out[i] = b[i - H_DIM];
  else if (i < 3 * H_DIM) out[i] = c[i - 2 * H_DIM];
}

__global__ void cls_copy_kernel(const float* __restrict__ vdn, float* __restrict__ cls)
{
  const int i = blockIdx.x * 256 + threadIdx.x;
  if (i < BATCH * OUT_DIM)
    cls[i] = vdn[(size_t)(i / OUT_DIM) * L_SEQ * OUT_DIM + (i % OUT_DIM)];
}

// ---------------- host ----------------
extern "C" void kernel_launch(void* const* d_in, const int* in_sizes, int n_in,
                              void* d_out, int out_size, void* d_ws, size_t ws_size,
                              hipStream_t stream)
{
  (void)in_sizes; (void)n_in; (void)out_size; (void)ws_size;
  const int*   ids   = (const int*)d_in[0];
  const int*   amask = (const int*)d_in[1];
  const float* wemb  = (const float*)d_in[2];
  const float* pemb  = (const float*)d_in[3];
  const float* elns  = (const float*)d_in[4];
  const float* elnb  = (const float*)d_in[5];
  const float* Wq    = (const float*)d_in[6];
  const float* bq    = (const float*)d_in[7];
  const float* Wk    = (const float*)d_in[8];
  const float* bk    = (const float*)d_in[9];
  const float* Wv    = (const float*)d_in[10];
  const float* bv    = (const float*)d_in[11];
  const float* Wo    = (const float*)d_in[12];
  const float* bo    = (const float*)d_in[13];
  const float* ln1s  = (const float*)d_in[14];
  const float* ln1b  = (const float*)d_in[15];
  const float* W1    = (const float*)d_in[16];
  const float* b1    = (const float*)d_in[17];
  const float* W2    = (const float*)d_in[18];
  const float* b2    = (const float*)d_in[19];
  const float* ln2s  = (const float*)d_in[20];
  const float* ln2b  = (const float*)d_in[21];
  const float* Wfc   = (const float*)d_in[22];
  const float* bfc   = (const float*)d_in[23];

  char* ws = (char*)d_ws;
  size_t off = 0;
  auto alloc = [&](size_t bytes) -> void* {
    void* p = ws + off;
    off += (bytes + 255) & ~(size_t)255;
    return p;
  };
  float* xf   = (float*)alloc((size_t)M_ROWS * H_DIM * 4);
  float* proj = (float*)alloc((size_t)M_ROWS * H_DIM * 4);
  u16* xb     = (u16*)alloc((size_t)M_ROWS * H_DIM * 2);
  u16* big    = (u16*)alloc((size_t)M_ROWS * FF_DIM * 2);  // qkv / ff1 time-share
  u16* attno  = (u16*)alloc((size_t)M_ROWS * H_DIM * 2);
  u16* wqkvT  = (u16*)alloc((size_t)QKV_LD * H_DIM * 2);
  u16* woT    = (u16*)alloc((size_t)H_DIM * H_DIM * 2);
  u16* w1T    = (u16*)alloc((size_t)FF_DIM * H_DIM * 2);
  u16* w2T    = (u16*)alloc((size_t)H_DIM * FF_DIM * 2);
  u16* wfcT   = (u16*)alloc((size_t)OUT_DIM * H_DIM * 2);
  float* bqkv = (float*)alloc(QKV_LD * 4);
  float* gsc  = (float*)alloc((size_t)BATCH * N_HEADS * L_SEQ * 4);
  float* gpm  = (float*)alloc((size_t)BATCH * N_HEADS * NSEG * 4);
  float* gps  = (float*)alloc((size_t)BATCH * N_HEADS * NSEG * 4);
  float* gpo  = (float*)alloc((size_t)BATCH * N_HEADS * NSEG * 4 * D_HEAD * 4);

  u16* qkvb = big;
  u16* ff1  = big;

  embed_ln_kernel<<<M_ROWS, 256, 0, stream>>>(ids, wemb, pemb, elns, elnb, xf, xb);

  for (int l = 0; l < 2; l++) {
    const size_t wof = (size_t)l * H_DIM * H_DIM;
    transpose_w_kernel<<<dim3(24, 24), 256, 0, stream>>>(Wq + wof, wqkvT, H_DIM, H_DIM);
    transpose_w_kernel<<<dim3(24, 24), 256, 0, stream>>>(Wk + wof, wqkvT + (size_t)H_DIM * H_DIM, H_DIM, H_DIM);
    transpose_w_kernel<<<dim3(24, 24), 256, 0, stream>>>(Wv + wof, wqkvT + (size_t)2 * H_DIM * H_DIM, H_DIM, H_DIM);
    transpose_w_kernel<<<dim3(24, 24), 256, 0, stream>>>(Wo + wof, woT, H_DIM, H_DIM);
    transpose_w_kernel<<<dim3(24, 96), 256, 0, stream>>>(W1 + (size_t)l * H_DIM * FF_DIM, w1T, H_DIM, FF_DIM);
    transpose_w_kernel<<<dim3(96, 24), 256, 0, stream>>>(W2 + (size_t)l * FF_DIM * H_DIM, w2T, FF_DIM, H_DIM);
    concat3_kernel<<<9, 256, 0, stream>>>(bq + l * H_DIM, bk + l * H_DIM, bv + l * H_DIM, bqkv);

    gemm_p<256, 1, 0><<<(M_ROWS / 256) * (QKV_LD / 256), 512, 0, stream>>>(
        xb, wqkvT, bqkv, nullptr, qkvb, QKV_LD, H_DIM);
    attn_local_kernel<<<BATCH * N_HEADS * N_CHUNK, 512, 0, stream>>>(qkvb, amask, attno);
    attn_g_score<<<dim3(NSEG, BATCH * N_HEADS), 256, 0, stream>>>(qkvb, amask, gsc, gpm);
    attn_g_pv<<<dim3(NSEG, BATCH * N_HEADS), 256, 0, stream>>>(qkvb, gsc, gpm, gps, gpo);
    attn_g_combine<<<BATCH * N_HEADS, 64, 0, stream>>>(gps, gpo, attno);
    gemm_p<128, 0, 0><<<(M_ROWS / 128) * (H_DIM / 128), 256, 0, stream>>>(
        attno, woT, bo + l * H_DIM, proj, nullptr, H_DIM, H_DIM);
    add_ln_kernel<<<M_ROWS, 256, 0, stream>>>(xf, proj, ln1s + l * H_DIM, ln1b + l * H_DIM, xb);
    gemm_p<256, 1, 1><<<(M_ROWS / 256) * (FF_DIM / 256), 512, 0, stream>>>(
        xb, w1T, b1 + l * FF_DIM, nullptr, ff1, FF_DIM, H_DIM);
    gemm_p<128, 0, 0><<<(M_ROWS / 128) * (H_DIM / 128), 256, 0, stream>>>(
        ff1, w2T, b2 + l * H_DIM, proj, nullptr, H_DIM, FF_DIM);
    add_ln_kernel<<<M_ROWS, 256, 0, stream>>>(xf, proj, ln2s + l * H_DIM, ln2b + l * H_DIM, xb);
  }

  transpose_w_kernel<<<dim3(24, 12), 256, 0, stream>>>(Wfc, wfcT, H_DIM, OUT_DIM);
  float* vdn = (float*)d_out;
  gemm_p<128, 0, 0><<<(M_ROWS / 128) * (OUT_DIM / 128), 256, 0, stream>>>(
      xb, wfcT, bfc, vdn, nullptr, OUT_DIM, H_DIM);
  cls_copy_kernel<<<3, 256, 0, stream>>>(vdn, vdn + (size_t)BATCH * L_SEQ * OUT_DIM);
}

// Round 6
// 675.127 us; speedup vs baseline: 1.2873x; 1.0703x over previous
//
#include <hip/hip_runtime.h>
#include <hip/hip_bf16.h>
#include <stdint.h>

#define L_SEQ 4096
#define H_DIM 768
#define N_HEADS 12
#define D_HEAD 64
#define N_CHUNK 32
#define CHUNK 128
#define FF_DIM 3072
#define OUT_DIM 384
#define BATCH 2
#define EPS_LN 1e-5f
#define M_ROWS (BATCH * L_SEQ)   /* 8192 */
#define QKV_LD (3 * H_DIM)       /* 2304 */
#define NSEG 16                   /* global-row segments: 4096/256 */

typedef unsigned short u16;
typedef __bf16 bx8 __attribute__((ext_vector_type(8)));
typedef float fx4 __attribute__((ext_vector_type(4)));
typedef u16 ux8 __attribute__((ext_vector_type(8)));

__device__ __forceinline__ u16 f2bf(float f) {
  union { float f; unsigned u; } x; x.f = f;
  unsigned r = x.u + 0x7fffu + ((x.u >> 16) & 1u);
  return (u16)(r >> 16);
}
__device__ __forceinline__ float bf2f(u16 v) {
  union { unsigned u; float f; } x; x.u = ((unsigned)v) << 16;
  return x.f;
}

__device__ __forceinline__ void gload16(const void* g, void* l) {
  __builtin_amdgcn_global_load_lds((const __attribute__((address_space(1))) void*)g,
                                   (__attribute__((address_space(3))) void*)l, 16, 0, 0);
}

// =====================================================================
// Simple TLP GEMM (m97 regime): 128x128 tile, BK=64, 4 waves (2x2),
// single-buffered 32 KiB LDS, 2 barriers per K-step, 3 blocks/CU.
// C(MxN) = A(MxK,bf16) @ Bt(NxK,bf16)^T + bias.
//
// LDS layout: As/Bs[128 rows][64 k] u16 (128 B row = 8 chunks of 16 B),
// chunk c of row r stored at position c ^ (r&7).
//   - staging: linear gload_lds dest; SOURCE column pre-swizzled:
//     lane covers row w*8+(lane>>3), source chunk (lane&7)^(lane>>3).
//   - read: frag (m-block, k-half h): row = *64+m*16+c16, chunk h*4+g,
//     swizzled position (h*4+g)^(c16&7)  [row&7 == c16&7].
//   Bank check (per b128): 64 lanes -> group (h*4+g)^(c16&7): each of the
//   8 four-bank groups gets exactly 8 lanes -> uniform, conflict-free.
// Latency hiding comes from 3 independent blocks/CU (m114), not intra-
// block pipelining (rounds 3-5 showed that regresses at 1 block/CU).
// =====================================================================
template<int OUT_BF16, int DO_GELU>
__global__ __launch_bounds__(256, 3)
void gemm_s(const u16* __restrict__ A, const u16* __restrict__ Bt,
            const float* __restrict__ bias,
            float* __restrict__ Cf, u16* __restrict__ Cb,
            int N, int K)
{
  __shared__ __align__(16) u16 As[128 * 64];
  __shared__ __align__(16) u16 Bs[128 * 64];
  const int tid = threadIdx.x;
  const int lane = tid & 63, w = tid >> 6;
  const int c16 = lane & 15, g = lane >> 4;
  const int wr = w >> 1, wc = w & 1;

  const int nbn = N >> 7;
  int id = blockIdx.x;
  id = (id & 7) * (gridDim.x >> 3) + (id >> 3);   // XCD swizzle (grids %8==0)
  const int bm = id / nbn, bn = id % nbn;

  // staging: lane covers row w*8+(lane>>3), 16B chunk (lane&7), pre-swizzled src
  const int srow = w * 8 + (lane >> 3);
  const int schunk = (lane & 7) ^ (lane >> 3);
  const u16* sA = A + (size_t)(bm * 128 + srow) * K + schunk * 8;
  const u16* sB = Bt + (size_t)(bn * 128 + srow) * K + schunk * 8;
  const int wdst = w * 512;   // u16, wave-uniform

  fx4 acc[4][4] = {};

  for (int k0 = 0; k0 < K; k0 += 64) {
    #pragma unroll
    for (int i = 0; i < 4; i++) {
      gload16(sA + (size_t)(i * 32) * K + k0, &As[i * 2048 + wdst]);
      gload16(sB + (size_t)(i * 32) * K + k0, &Bs[i * 2048 + wdst]);
    }
    __syncthreads();   // vmcnt(0) drain; hidden by other blocks on this CU
    #pragma unroll
    for (int h = 0; h < 2; h++) {
      bx8 af[4], bf[4];
      #pragma unroll
      for (int m = 0; m < 4; m++) {
        const int row = wr * 64 + m * 16 + c16;
        af[m] = *(const bx8*)&As[row * 64 + (((h << 2) + g) ^ (c16 & 7)) * 8];
      }
      #pragma unroll
      for (int n = 0; n < 4; n++) {
        const int row = wc * 64 + n * 16 + c16;
        bf[n] = *(const bx8*)&Bs[row * 64 + (((h << 2) + g) ^ (c16 & 7)) * 8];
      }
      #pragma unroll
      for (int m = 0; m < 4; m++)
        #pragma unroll
        for (int n = 0; n < 4; n++)
          acc[m][n] = __builtin_amdgcn_mfma_f32_16x16x32_bf16(af[m], bf[n], acc[m][n], 0, 0, 0);
    }
    __syncthreads();
  }

  const int row0 = bm * 128 + wr * 64 + g * 4;
  const int col0 = bn * 128 + wc * 64 + c16;
  #pragma unroll
  for (int n = 0; n < 4; n++) {
    const int col = col0 + n * 16;
    const float bb = bias[col];
    #pragma unroll
    for (int m = 0; m < 4; m++) {
      #pragma unroll
      for (int r = 0; r < 4; r++) {
        float y = acc[m][n][r] + bb;
        if (DO_GELU) {
          const float tt = y;
          y = 0.5f * tt * (1.0f + tanhf(0.7978845608f * (tt + 0.044715f * tt * tt * tt)));
        }
        const size_t idx = (size_t)(row0 + m * 16 + r) * N + col;
        if (OUT_BF16) Cb[idx] = f2bf(y);
        else Cf[idx] = y;
      }
    }
  }
}

// ---------------- Local (windowed) attention ----------------
#define V_STR 424

__global__ __launch_bounds__(512, 2)
void attn_local_kernel(const u16* __restrict__ qkv, const int* __restrict__ amask,
                       u16* __restrict__ attnout)
{
  __shared__ __align__(16) u16 Vlds[64 * V_STR];        // V^T: [d][key]
  __shared__ __align__(16) u16 Plds[8 * 16 * V_STR];    // per-wave P: [q][key]

  const int tid = threadIdx.x;
  const int lane = tid & 63, w = tid >> 6;
  const int c16 = lane & 15, g = lane >> 4;

  const int bh = blockIdx.x >> 5;
  const int n = blockIdx.x & 31;
  const int b = bh / N_HEADS, h = bh % N_HEADS;

  const u16* qkvb = qkv + (size_t)b * L_SEQ * QKV_LD + h * D_HEAD;
  const int chunk_lo = n * CHUNK - CHUNK;

  for (int idx = tid; idx < 416 * 8; idx += 512) {
    const int j = idx >> 3, d8 = (idx & 7) * 8;
    if (j >= 385) {
      #pragma unroll
      for (int i = 0; i < 8; i++) Vlds[(d8 + i) * V_STR + j] = 0;
    } else {
      int pos = (j == 384) ? 0 : chunk_lo + j;
      if (pos < 0 || pos >= L_SEQ) pos = 0;
      ux8 vv = *(const ux8*)(qkvb + (size_t)pos * QKV_LD + 2 * H_DIM + d8);
      #pragma unroll
      for (int i = 0; i < 8; i++) Vlds[(d8 + i) * V_STR + j] = vv[i];
    }
  }

  const int qrow = n * CHUNK + w * 16 + c16;
  const u16* qp = qkvb + (size_t)qrow * QKV_LD + g * 8;
  const bx8 aq0 = *(const bx8*)qp;
  const bx8 aq1 = *(const bx8*)(qp + 32);

  unsigned kvm = 0;
  #pragma unroll
  for (int kf = 0; kf < 24; kf++) {
    const int pos = chunk_lo + kf * 16 + c16;
    bool ok = (pos >= 1) && (pos < L_SEQ);
    if (ok) ok = (amask[b * L_SEQ + pos] > 0);
    kvm |= ((unsigned)ok) << kf;
  }

  fx4 s[26];
  #pragma unroll
  for (int kf = 0; kf < 25; kf++) {
    int pos = (kf == 24) ? 0 : chunk_lo + kf * 16 + c16;
    if (pos < 0 || pos >= L_SEQ) pos = 0;
    const u16* kp = qkvb + (size_t)pos * QKV_LD + H_DIM + g * 8;
    const bx8 b0 = *(const bx8*)kp;
    const bx8 b1 = *(const bx8*)(kp + 32);
    fx4 a = {};
    a = __builtin_amdgcn_mfma_f32_16x16x32_bf16(aq0, b0, a, 0, 0, 0);
    a = __builtin_amdgcn_mfma_f32_16x16x32_bf16(aq1, b1, a, 0, 0, 0);
    s[kf] = a;
  }

  const int cq = w * 16 + g * 4;
  float mx[4], sm[4];
  #pragma unroll
  for (int r = 0; r < 4; r++) mx[r] = -3.0e38f;
  #pragma unroll
  for (int kf = 0; kf < 25; kf++) {
    const int j = kf * 16 + c16;
    const bool kv = (kf < 24) ? (((kvm >> kf) & 1u) != 0) : (c16 == 0);
    #pragma unroll
    for (int r = 0; r < 4; r++) {
      const int c = cq + r;
      const bool keep = kv && (kf == 24 || (j >= c && j <= c + 256));
      const float val = keep ? s[kf][r] * 0.125f : -1.0e9f;
      s[kf][r] = val;
      mx[r] = fmaxf(mx[r], val);
    }
  }
  #pragma unroll
  for (int r = 0; r < 4; r++) {
    float m = mx[r];
    m = fmaxf(m, __shfl_xor(m, 1));
    m = fmaxf(m, __shfl_xor(m, 2));
    m = fmaxf(m, __shfl_xor(m, 4));
    m = fmaxf(m, __shfl_xor(m, 8));
    mx[r] = m;
    sm[r] = 0.f;
  }
  #pragma unroll
  for (int kf = 0; kf < 25; kf++)
    #pragma unroll
    for (int r = 0; r < 4; r++) {
      const float p = __expf(s[kf][r] - mx[r]);
      s[kf][r] = p;
      sm[r] += p;
    }
  float rinv[4];
  #pragma unroll
  for (int r = 0; r < 4; r++) {
    float t = sm[r];
    t += __shfl_xor(t, 1);
    t += __shfl_xor(t, 2);
    t += __shfl_xor(t, 4);
    t += __shfl_xor(t, 8);
    rinv[r] = 1.0f / t;
  }
  s[25] = (fx4){0.f, 0.f, 0.f, 0.f};

  u16* pb = Plds + (size_t)w * 16 * V_STR;
  #pragma unroll
  for (int kf = 0; kf < 26; kf++) {
    const int j = kf * 16 + c16;
    #pragma unroll
    for (int r = 0; r < 4; r++)
      pb[(g * 4 + r) * V_STR + j] = f2bf(s[kf][r]);
  }
  __syncthreads();

  fx4 o[4] = {};
  const u16* pr = Plds + (size_t)(w * 16 + c16) * V_STR + g * 8;
  #pragma unroll
  for (int kt = 0; kt < 13; kt++) {
    const bx8 pa = *(const bx8*)(pr + kt * 32);
    #pragma unroll
    for (int df = 0; df < 4; df++) {
      const bx8 vvf = *(const bx8*)&Vlds[(df * 16 + c16) * V_STR + kt * 32 + g * 8];
      o[df] = __builtin_amdgcn_mfma_f32_16x16x32_bf16(pa, vvf, o[df], 0, 0, 0);
    }
  }

  u16* ob = attnout + (size_t)b * L_SEQ * H_DIM + h * D_HEAD;
  const int posq = n * CHUNK + w * 16 + g * 4;
  #pragma unroll
  for (int df = 0; df < 4; df++)
    #pragma unroll
    for (int r = 0; r < 4; r++)
      ob[(size_t)(posq + r) * H_DIM + df * 16 + c16] = f2bf(o[df][r] * rinv[r]);
}

// ---------------- Global row (query position 0) ----------------
__global__ __launch_bounds__(256)
void attn_g_score(const u16* __restrict__ qkv, const int* __restrict__ amask,
                  float* __restrict__ sbuf, float* __restrict__ pmax)
{
  __shared__ float qs[D_HEAD];
  __shared__ float red[4];
  const int seg = blockIdx.x, bh = blockIdx.y;
  const int b = bh / N_HEADS, h = bh % N_HEADS;
  const u16* base = qkv + (size_t)b * L_SEQ * QKV_LD + h * D_HEAD;
  const int tid = threadIdx.x;

  if (tid < D_HEAD) qs[tid] = bf2f(base[tid]);
  __syncthreads();

  const int l = seg * 256 + tid;
  const ux8* kp = (const ux8*)(base + (size_t)l * QKV_LD + H_DIM);
  float dot = 0.f;
  #pragma unroll
  for (int i = 0; i < 8; i++) {
    const ux8 kv = kp[i];
    #pragma unroll
    for (int j = 0; j < 8; j++) dot += qs[i * 8 + j] * bf2f(kv[j]);
  }
  float sv = dot * 0.125f;
  if (amask[b * L_SEQ + l] == 0) sv = -1.0e9f;
  sbuf[(size_t)bh * L_SEQ + l] = sv;

  float m = sv;
  #pragma unroll
  for (int off = 32; off > 0; off >>= 1) m = fmaxf(m, __shfl_xor(m, off));
  if ((tid & 63) == 0) red[tid >> 6] = m;
  __syncthreads();
  if (tid == 0)
    pmax[bh * NSEG + seg] = fmaxf(fmaxf(red[0], red[1]), fmaxf(red[2], red[3]));
}

__global__ __launch_bounds__(256)
void attn_g_pv(const u16* __restrict__ qkv, const float* __restrict__ sbuf,
               const float* __restrict__ pmax, float* __restrict__ psum,
               float* __restrict__ po)
{
  __shared__ float es[256];
  __shared__ float red[4];
  const int seg = blockIdx.x, bh = blockIdx.y;
  const int b = bh / N_HEADS, h = bh % N_HEADS;
  const int tid = threadIdx.x;

  float M = -3.0e38f;
  #pragma unroll
  for (int i = 0; i < NSEG; i++) M = fmaxf(M, pmax[bh * NSEG + i]);

  const int l = seg * 256 + tid;
  const float e = __expf(sbuf[(size_t)bh * L_SEQ + l] - M);
  es[tid] = e;

  float t = e;
  #pragma unroll
  for (int off = 32; off > 0; off >>= 1) t += __shfl_xor(t, off);
  if ((tid & 63) == 0) red[tid >> 6] = t;
  __syncthreads();
  if (tid == 0) psum[bh * NSEG + seg] = red[0] + red[1] + red[2] + red[3];

  const int d = tid & 63, grp = tid >> 6;
  const u16* vb = qkv + (size_t)b * L_SEQ * QKV_LD + h * D_HEAD + 2 * H_DIM + d;
  float acc = 0.f;
  #pragma unroll 4
  for (int i = 0; i < 64; i++) {
    const int ll = seg * 256 + grp * 64 + i;
    acc += es[grp * 64 + i] * bf2f(vb[(size_t)ll * QKV_LD]);
  }
  po[(((size_t)bh * NSEG + seg) * 4 + grp) * D_HEAD + d] = acc;
}

__global__ __launch_bounds__(64)
void attn_g_combine(const float* __restrict__ psum, const float* __restrict__ po,
                    u16* __restrict__ attnout)
{
  const int bh = blockIdx.x;
  const int b = bh / N_HEADS, h = bh % N_HEADS;
  const int d = threadIdx.x;
  float S = 0.f;
  #pragma unroll
  for (int i = 0; i < NSEG; i++) S += psum[bh * NSEG + i];
  float acc = 0.f;
  #pragma unroll
  for (int i = 0; i < NSEG * 4; i++)
    acc += po[((size_t)bh * NSEG * 4 + i) * D_HEAD + d];
  attnout[(size_t)b * L_SEQ * H_DIM + h * D_HEAD + d] = f2bf(acc / S);
}

// ---------------- LayerNorm kernels ----------------
__device__ __forceinline__ void block_stats(float sum, float sq, float* red,
                                            float& mean, float& rstd)
{
  const int lane = threadIdx.x & 63, wv = threadIdx.x >> 6;
  #pragma unroll
  for (int off = 32; off > 0; off >>= 1) {
    sum += __shfl_xor(sum, off);
    sq  += __shfl_xor(sq, off);
  }
  if (lane == 0) { red[wv] = sum; red[4 + wv] = sq; }
  __syncthreads();
  sum = red[0] + red[1] + red[2] + red[3];
  sq  = red[4] + red[5] + red[6] + red[7];
  mean = sum * (1.0f / H_DIM);
  const float var = sq * (1.0f / H_DIM) - mean * mean;
  rstd = rsqrtf(var + EPS_LN);
}

__global__ __launch_bounds__(256)
void embed_ln_kernel(const int* __restrict__ ids, const float* __restrict__ wemb,
                     const float* __restrict__ pemb, const float* __restrict__ gam,
                     const float* __restrict__ bet, float* __restrict__ xf,
                     u16* __restrict__ xb)
{
  __shared__ float red[8];
  const int row = blockIdx.x, tid = threadIdx.x;
  const int l = row & (L_SEQ - 1);
  const int id = ids[row];
  float v[3]; float sum = 0.f, sq = 0.f;
  #pragma unroll
  for (int i = 0; i < 3; i++) {
    const int c = tid + i * 256;
    const float t = wemb[(size_t)id * H_DIM + c] + pemb[(size_t)l * H_DIM + c];
    v[i] = t; sum += t; sq += t * t;
  }
  float mean, rstd;
  block_stats(sum, sq, red, mean, rstd);
  #pragma unroll
  for (int i = 0; i < 3; i++) {
    const int c = tid + i * 256;
    const float y = (v[i] - mean) * rstd * gam[c] + bet[c];
    xf[(size_t)row * H_DIM + c] = y;
    xb[(size_t)row * H_DIM + c] = f2bf(y);
  }
}

__global__ __launch_bounds__(256)
void add_ln_kernel(float* xio, const float* __restrict__ yin,
                   const float* __restrict__ gam, const float* __restrict__ bet,
                   u16* __restrict__ xb)
{
  __shared__ float red[8];
  const int row = blockIdx.x, tid = threadIdx.x;
  float v[3]; float sum = 0.f, sq = 0.f;
  #pragma unroll
  for (int i = 0; i < 3; i++) {
    const int c = tid + i * 256;
    const float t = xio[(size_t)row * H_DIM + c] + yin[(size_t)row * H_DIM + c];
    v[i] = t; sum += t; sq += t * t;
  }
  float mean, rstd;
  block_stats(sum, sq, red, mean, rstd);
  #pragma unroll
  for (int i = 0; i < 3; i++) {
    const int c = tid + i * 256;
    const float y = (v[i] - mean) * rstd * gam[c] + bet[c];
    xio[(size_t)row * H_DIM + c] = y;
    xb[(size_t)row * H_DIM + c] = f2bf(y);
  }
}

// ---------------- weight transpose fp32 -> bf16 ----------------
__global__ __launch_bounds__(256)
void transpose_w_kernel(const float* __restrict__ W, u16* __restrict__ Wt, int K, int N)
{
  __shared__ float tile[32][33];
  const int k0 = blockIdx.x * 32, n0 = blockIdx.y * 32;
  const int tx = threadIdx.x & 31, ty = threadIdx.x >> 5;
  #pragma unroll
  for (int i = 0; i < 32; i += 8)
    tile[ty + i][tx] = W[(size_t)(k0 + ty + i) * N + n0 + tx];
  __syncthreads();
  #pragma unroll
  for (int i = 0; i < 32; i += 8)
    Wt[(size_t)(n0 + ty + i) * K + k0 + tx] = f2bf(tile[tx][ty + i]);
}

__global__ void concat3_kernel(const float* __restrict__ a, const float* __restrict__ b,
                               const float* __restrict__ c, float* __restrict__ out)
{
  const int i = blockIdx.x * 256 + threadIdx.x;
  if (i < H_DIM) out[i] = a[i];
  else if (i < 2 * H_DIM) out[i] = b[i - H_DIM];
  else if (i < 3 * H_DIM) out[i] = c[i - 2 * H_DIM];
}

__global__ void cls_copy_kernel(const float* __restrict__ vdn, float* __restrict__ cls)
{
  const int i = blockIdx.x * 256 + threadIdx.x;
  if (i < BATCH * OUT_DIM)
    cls[i] = vdn[(size_t)(i / OUT_DIM) * L_SEQ * OUT_DIM + (i % OUT_DIM)];
}

// ---------------- host ----------------
extern "C" void kernel_launch(void* const* d_in, const int* in_sizes, int n_in,
                              void* d_out, int out_size, void* d_ws, size_t ws_size,
                              hipStream_t stream)
{
  (void)in_sizes; (void)n_in; (void)out_size; (void)ws_size;
  const int*   ids   = (const int*)d_in[0];
  const int*   amask = (const int*)d_in[1];
  const float* wemb  = (const float*)d_in[2];
  const float* pemb  = (const float*)d_in[3];
  const float* elns  = (const float*)d_in[4];
  const float* elnb  = (const float*)d_in[5];
  const float* Wq    = (const float*)d_in[6];
  const float* bq    = (const float*)d_in[7];
  const float* Wk    = (const float*)d_in[8];
  const float* bk    = (const float*)d_in[9];
  const float* Wv    = (const float*)d_in[10];
  const float* bv    = (const float*)d_in[11];
  const float* Wo    = (const float*)d_in[12];
  const float* bo    = (const float*)d_in[13];
  const float* ln1s  = (const float*)d_in[14];
  const float* ln1b  = (const float*)d_in[15];
  const float* W1    = (const float*)d_in[16];
  const float* b1    = (const float*)d_in[17];
  const float* W2    = (const float*)d_in[18];
  const float* b2    = (const float*)d_in[19];
  const float* ln2s  = (const float*)d_in[20];
  const float* ln2b  = (const float*)d_in[21];
  const float* Wfc   = (const float*)d_in[22];
  const float* bfc   = (const float*)d_in[23];

  char* ws = (char*)d_ws;
  size_t off = 0;
  auto alloc = [&](size_t bytes) -> void* {
    void* p = ws + off;
    off += (bytes + 255) & ~(size_t)255;
    return p;
  };
  float* xf   = (float*)alloc((size_t)M_ROWS * H_DIM * 4);
  float* proj = (float*)alloc((size_t)M_ROWS * H_DIM * 4);
  u16* xb     = (u16*)alloc((size_t)M_ROWS * H_DIM * 2);
  u16* big    = (u16*)alloc((size_t)M_ROWS * FF_DIM * 2);  // qkv / ff1 time-share
  u16* attno  = (u16*)alloc((size_t)M_ROWS * H_DIM * 2);
  u16* wqkvT  = (u16*)alloc((size_t)QKV_LD * H_DIM * 2);
  u16* woT    = (u16*)alloc((size_t)H_DIM * H_DIM * 2);
  u16* w1T    = (u16*)alloc((size_t)FF_DIM * H_DIM * 2);
  u16* w2T    = (u16*)alloc((size_t)H_DIM * FF_DIM * 2);
  u16* wfcT   = (u16*)alloc((size_t)OUT_DIM * H_DIM * 2);
  float* bqkv = (float*)alloc(QKV_LD * 4);
  float* gsc  = (float*)alloc((size_t)BATCH * N_HEADS * L_SEQ * 4);
  float* gpm  = (float*)alloc((size_t)BATCH * N_HEADS * NSEG * 4);
  float* gps  = (float*)alloc((size_t)BATCH * N_HEADS * NSEG * 4);
  float* gpo  = (float*)alloc((size_t)BATCH * N_HEADS * NSEG * 4 * D_HEAD * 4);

  u16* qkvb = big;
  u16* ff1  = big;

  embed_ln_kernel<<<M_ROWS, 256, 0, stream>>>(ids, wemb, pemb, elns, elnb, xf, xb);

  for (int l = 0; l < 2; l++) {
    const size_t wof = (size_t)l * H_DIM * H_DIM;
    transpose_w_kernel<<<dim3(24, 24), 256, 0, stream>>>(Wq + wof, wqkvT, H_DIM, H_DIM);
    transpose_w_kernel<<<dim3(24, 24), 256, 0, stream>>>(Wk + wof, wqkvT + (size_t)H_DIM * H_DIM, H_DIM, H_DIM);
    transpose_w_kernel<<<dim3(24, 24), 256, 0, stream>>>(Wv + wof, wqkvT + (size_t)2 * H_DIM * H_DIM, H_DIM, H_DIM);
    transpose_w_kernel<<<dim3(24, 24), 256, 0, stream>>>(Wo + wof, woT, H_DIM, H_DIM);
    transpose_w_kernel<<<dim3(24, 96), 256, 0, stream>>>(W1 + (size_t)l * H_DIM * FF_DIM, w1T, H_DIM, FF_DIM);
    transpose_w_kernel<<<dim3(96, 24), 256, 0, stream>>>(W2 + (size_t)l * FF_DIM * H_DIM, w2T, FF_DIM, H_DIM);
    concat3_kernel<<<9, 256, 0, stream>>>(bq + l * H_DIM, bk + l * H_DIM, bv + l * H_DIM, bqkv);

    gemm_s<1, 0><<<(M_ROWS / 128) * (QKV_LD / 128), 256, 0, stream>>>(
        xb, wqkvT, bqkv, nullptr, qkvb, QKV_LD, H_DIM);
    attn_local_kernel<<<BATCH * N_HEADS * N_CHUNK, 512, 0, stream>>>(qkvb, amask, attno);
    attn_g_score<<<dim3(NSEG, BATCH * N_HEADS), 256, 0, stream>>>(qkvb, amask, gsc, gpm);
    attn_g_pv<<<dim3(NSEG, BATCH * N_HEADS), 256, 0, stream>>>(qkvb, gsc, gpm, gps, gpo);
    attn_g_combine<<<BATCH * N_HEADS, 64, 0, stream>>>(gps, gpo, attno);
    gemm_s<0, 0><<<(M_ROWS / 128) * (H_DIM / 128), 256, 0, stream>>>(
        attno, woT, bo + l * H_DIM, proj, nullptr, H_DIM, H_DIM);
    add_ln_kernel<<<M_ROWS, 256, 0, stream>>>(xf, proj, ln1s + l * H_DIM, ln1b + l * H_DIM, xb);
    gemm_s<1, 1><<<(M_ROWS / 128) * (FF_DIM / 128), 256, 0, stream>>>(
        xb, w1T, b1 + l * FF_DIM, nullptr, ff1, FF_DIM, H_DIM);
    gemm_s<0, 0><<<(M_ROWS / 128) * (H_DIM / 128), 256, 0, stream>>>(
        ff1, w2T, b2 + l * H_DIM, proj, nullptr, H_DIM, FF_DIM);
    add_ln_kernel<<<M_ROWS, 256, 0, stream>>>(xf, proj, ln2s + l * H_DIM, ln2b + l * H_DIM, xb);
  }

  transpose_w_kernel<<<dim3(24, 12), 256, 0, stream>>>(Wfc, wfcT, H_DIM, OUT_DIM);
  float* vdn = (float*)d_out;
  gemm_s<0, 0><<<(M_ROWS / 128) * (OUT_DIM / 128), 256, 0, stream>>>(
      xb, wfcT, bfc, vdn, nullptr, OUT_DIM, H_DIM);
  cls_copy_kernel<<<3, 256, 0, stream>>>(vdn, vdn + (size_t)BATCH * L_SEQ * OUT_DIM);
}